// Round 9
// baseline (3083.831 us; speedup 1.0000x reference)
//
#include <hip/hip_runtime.h>
#include <hip/hip_bf16.h>

// Problem constants (fixed by the reference)
#define BB 1024
#define NN 512
#define MI 512
#define ME 16
#define ALPHA 0.05f
#define NS_ITERS 8   // Gershgorin c0 -> r~0.9; 0.9^256 ~ 7e-12: converged
#define ADMM_IT 15

typedef __attribute__((ext_vector_type(8))) short short8;
typedef __attribute__((ext_vector_type(4))) float float4v;

__device__ inline short f2bf(float v) {
    __hip_bfloat16 b = __float2bfloat16(v);
    return *reinterpret_cast<short*>(&b);
}
__device__ inline float bf2f(short s) {
    __hip_bfloat16 b = *reinterpret_cast<__hip_bfloat16*>(&s);
    return __bfloat162float(b);
}
__device__ inline void split_store(float v, short* __restrict__ hi, short* __restrict__ lo, size_t idx) {
    short h = f2bf(v);
    hi[idx] = h;
    lo[idx] = f2bf(v - bf2f(h));
}

// ---------------- dtype auto-detect ----------------
__global__ void detect_dtype_k(const unsigned short* __restrict__ g_raw,
                               float* __restrict__ flag) {
    __shared__ int cnt;
    int tid = threadIdx.x;
    if (tid == 0) cnt = 0;
    __syncthreads();
    int local = 0;
    for (int i = tid; i < 8192; i += 256) {
        int e = (g_raw[i] >> 7) & 0xFF;
        if (e >= 0x83) local++;
    }
    atomicAdd(&cnt, local);
    __syncthreads();
    if (tid == 0) flag[0] = (cnt < 64) ? 1.0f : 0.0f;  // 1 => bf16 inputs
}

// ---------------- fused ingest (also zeroes rs accumulator) ----------------
__global__ void ingest_all_k(const void* __restrict__ c_raw, const void* __restrict__ G_raw,
                             const void* __restrict__ h_raw, const void* __restrict__ A_raw,
                             const void* __restrict__ b_raw,
                             float* __restrict__ cF, short* __restrict__ xh, short* __restrict__ xl,
                             float* __restrict__ GF, short* __restrict__ GFh, short* __restrict__ GFl,
                             float* __restrict__ hF, float* __restrict__ AF, float* __restrict__ bF,
                             float* __restrict__ rs, const float* __restrict__ flag) {
    int i = blockIdx.x * 256 + threadIdx.x;
    bool isbf = flag[0] > 0.5f;
    #define RD(p, idx) (isbf ? __bfloat162float(((const __hip_bfloat16*)(p))[idx]) : ((const float*)(p))[idx])
    if (i < BB * NN) { float v = RD(c_raw, i); cF[i] = v; split_store(v, xh, xl, i); }
    if (i < MI * NN) { float v = RD(G_raw, i); GF[i] = v; split_store(v, GFh, GFl, i); }
    if (i < MI)      hF[i] = RD(h_raw, i);
    if (i < ME * NN) AF[i] = RD(A_raw, i);
    if (i < ME)      bF[i] = RD(b_raw, i);
    if (i < NN)      rs[i] = 0.f;
    #undef RD
}

// transpose 512x512 f32 -> bf16 hi/lo planes
__global__ void transpose_split_k(const float* __restrict__ src,
                                  short* __restrict__ dh, short* __restrict__ dl) {
    __shared__ float t[32][33];
    int bx = blockIdx.x * 32, by = blockIdx.y * 32;
    int tx = threadIdx.x & 31, ty0 = threadIdx.x >> 5;
    for (int i = ty0; i < 32; i += 8) t[i][tx] = src[(by + i) * 512 + bx + tx];
    __syncthreads();
    for (int i = ty0; i < 32; i += 8)
        split_store(t[tx][i], dh, dl, (size_t)(bx + i) * 512 + by + tx);
}

// ---------------- LDS-staged 16x64 tile GEMM (K=512), used by precompute ------
#define CH 128
#define LDC 136

__device__ __forceinline__ void tile16(
    const short* __restrict__ Ahi, const short* __restrict__ Alo,
    const short* __restrict__ Bhi, const short* __restrict__ Blo,
    int m0, int n0, short* __restrict__ As, short* __restrict__ Bs,
    float4v* __restrict__ out)
{
    const int tid = threadIdx.x;
    const int wv = tid >> 6, ln = tid & 63;
    const int quad = ln >> 4, lr = ln & 15;

    float4v acc1 = {0.f,0.f,0.f,0.f}, acc2 = {0.f,0.f,0.f,0.f};

    short8 pa[2], pb[8];
    #pragma unroll
    for (int i = 0; i < 2; ++i) {
        int s = tid + 256 * i; int pl = s >> 8, rem = s & 255, row = rem >> 4, oct = rem & 15;
        const short* P = pl ? Alo : Ahi;
        pa[i] = *(const short8*)(P + (size_t)(m0 + row) * 512 + oct * 8);
    }
    #pragma unroll
    for (int i = 0; i < 8; ++i) {
        int s = tid + 256 * i; int pl = s >> 10, rem = s & 1023, row = rem >> 4, oct = rem & 15;
        const short* P = pl ? Blo : Bhi;
        pb[i] = *(const short8*)(P + (size_t)(n0 + row) * 512 + oct * 8);
    }

    for (int c = 0; c < 4; ++c) {
        __syncthreads();
        #pragma unroll
        for (int i = 0; i < 2; ++i) {
            int s = tid + 256 * i; int pl = s >> 8, rem = s & 255, row = rem >> 4, oct = rem & 15;
            *(short8*)&As[pl * (16 * LDC) + row * LDC + oct * 8] = pa[i];
        }
        #pragma unroll
        for (int i = 0; i < 8; ++i) {
            int s = tid + 256 * i; int pl = s >> 10, rem = s & 1023, row = rem >> 4, oct = rem & 15;
            *(short8*)&Bs[pl * (64 * LDC) + row * LDC + oct * 8] = pb[i];
        }
        __syncthreads();
        if (c + 1 < 4) {
            int kb = (c + 1) * CH;
            #pragma unroll
            for (int i = 0; i < 2; ++i) {
                int s = tid + 256 * i; int pl = s >> 8, rem = s & 255, row = rem >> 4, oct = rem & 15;
                const short* P = pl ? Alo : Ahi;
                pa[i] = *(const short8*)(P + (size_t)(m0 + row) * 512 + kb + oct * 8);
            }
            #pragma unroll
            for (int i = 0; i < 8; ++i) {
                int s = tid + 256 * i; int pl = s >> 10, rem = s & 1023, row = rem >> 4, oct = rem & 15;
                const short* P = pl ? Blo : Bhi;
                pb[i] = *(const short8*)(P + (size_t)(n0 + row) * 512 + kb + oct * 8);
            }
        }
        #pragma unroll
        for (int ks = 0; ks < 4; ++ks) {
            int ko = (ks * 4 + quad) * 8;
            short8 ah = *(const short8*)&As[lr * LDC + ko];
            short8 al = *(const short8*)&As[16 * LDC + lr * LDC + ko];
            short8 bh = *(const short8*)&Bs[(wv * 16 + lr) * LDC + ko];
            short8 bl = *(const short8*)&Bs[64 * LDC + (wv * 16 + lr) * LDC + ko];
            acc1 = __builtin_amdgcn_mfma_f32_16x16x32_bf16(ah, bh, acc1, 0, 0, 0);
            acc2 = __builtin_amdgcn_mfma_f32_16x16x32_bf16(ah, bl, acc2, 0, 0, 0);
            acc2 = __builtin_amdgcn_mfma_f32_16x16x32_bf16(al, bh, acc2, 0, 0, 0);
        }
    }
    out[0] = acc1 + acc2;
}

// epi: 0 = f32 + planes; 1 = +I, f32 + planes, rs row-abs atomics (M build); 9 = planes only
__global__ __launch_bounds__(256) void gemm16_k(
    const short* __restrict__ Ahi, const short* __restrict__ Alo,
    const short* __restrict__ Bhi, const short* __restrict__ Blo,
    float* __restrict__ C, short* __restrict__ Chi, short* __restrict__ Clo,
    float* __restrict__ rs, int epi)
{
    __shared__ short smem[2 * 16 * LDC + 2 * 64 * LDC];
    short* As = smem;
    short* Bs = smem + 2 * 16 * LDC;
    int m0 = blockIdx.y * 16, n0 = blockIdx.x * 64;
    float4v out[1];
    tile16(Ahi, Alo, Bhi, Blo, m0, n0, As, Bs, out);
    int ln = threadIdx.x & 63, wv = threadIdx.x >> 6;
    int quad = ln >> 4, lr = ln & 15;
    #pragma unroll
    for (int r = 0; r < 4; ++r) {
        int m = m0 + quad * 4 + r, n = n0 + wv * 16 + lr;
        size_t idx = (size_t)m * 512 + n;
        float v = out[0][r];
        if (epi == 1) v += (m == n) ? 1.f : 0.f;
        if (epi != 9) C[idx] = v;
        split_store(v, Chi, Clo, idx);
        if (epi == 1) {
            float s = fabsf(v);
            s += __shfl_xor(s, 1); s += __shfl_xor(s, 2);
            s += __shfl_xor(s, 4); s += __shfl_xor(s, 8);
            if (lr == 0) atomicAdd(&rs[m], s);
        }
    }
}

// X0 = c0 * I with c0 = 2/(1+max rs) computed per-block
__global__ void initX_k(const float* __restrict__ rs, float* __restrict__ X,
                        short* __restrict__ Xh, short* __restrict__ Xl) {
    int ln = threadIdx.x & 63;
    float mx = 0.f;
    #pragma unroll
    for (int i = 0; i < 8; ++i) mx = fmaxf(mx, rs[ln + i * 64]);
    for (int off = 32; off; off >>= 1) mx = fmaxf(mx, __shfl_down(mx, off));
    float c0 = 2.0f / (1.0f + __shfl(mx, 0));
    #pragma unroll
    for (int j = 0; j < 4; ++j) {
        int idx = blockIdx.x * 1024 + j * 256 + threadIdx.x;
        int r = idx >> 9, cc = idx & 511;
        float v = (r == cc) ? c0 : 0.f;
        X[idx] = v;
        split_store(v, Xh, Xl, idx);
    }
}

// ---------------- row-local GEMM sweep (16 rows x 512 cols, K=512) -----------
// A from LDS planes tp[2][16][520]; B from global planes. acc[ct] covers
// n = wave*128 + ct*16 + (lane&15), rows m_local = (lane>>4)*4 + r.
#define TPS 520          // LDS row stride in shorts (1040B: 16B-aligned, 2-way banks)
#define TPP (16 * TPS)   // plane stride

__device__ __forceinline__ void row_gemm(
    const short* __restrict__ Bh, const short* __restrict__ Bl,
    const short* __restrict__ tp, int w, int quad, int lr,
    float4v* __restrict__ acc)
{
    float4v a2[8];
    #pragma unroll
    for (int ct = 0; ct < 8; ++ct) { acc[ct] = (float4v){0.f,0.f,0.f,0.f}; a2[ct] = acc[ct]; }
    for (int kw = 0; kw < 16; ++kw) {
        int ko = kw * 32 + quad * 8;
        short8 ah = *(const short8*)&tp[lr * TPS + ko];
        short8 al = *(const short8*)&tp[TPP + lr * TPS + ko];
        #pragma unroll
        for (int ct = 0; ct < 8; ++ct) {
            size_t bo = (size_t)(w * 128 + ct * 16 + lr) * 512 + ko;
            short8 bh = *(const short8*)(Bh + bo);
            short8 bl = *(const short8*)(Bl + bo);
            acc[ct] = __builtin_amdgcn_mfma_f32_16x16x32_bf16(ah, bh, acc[ct], 0, 0, 0);
            a2[ct]  = __builtin_amdgcn_mfma_f32_16x16x32_bf16(ah, bl, a2[ct], 0, 0, 0);
            a2[ct]  = __builtin_amdgcn_mfma_f32_16x16x32_bf16(al, bh, a2[ct], 0, 0, 0);
        }
    }
    #pragma unroll
    for (int ct = 0; ct < 8; ++ct) acc[ct] = acc[ct] + a2[ct];
}

__device__ __forceinline__ void split_lds(float v, short* __restrict__ tp, int ml, int n) {
    short h = f2bf(v);
    tp[ml * TPS + n] = h;
    tp[TPP + ml * TPS + n] = f2bf(v - bf2f(h));
}

// ---------------- NS pair kernel: X' = 2X - (X M) X, rows-local --------------
// All iterates are symmetric polynomials in symmetric M, so row-local NT GEMMs
// with B = M / B = X are exact. One launch per NS iteration, 32 blocks.
__global__ __launch_bounds__(256, 1) void ns_pair_k(
    const short* __restrict__ Xh, const short* __restrict__ Xl, const float* __restrict__ Xf,
    const short* __restrict__ Mh, const short* __restrict__ Ml,
    float* __restrict__ Xnf, short* __restrict__ Xnh, short* __restrict__ Xnl)
{
    __shared__ short tp[2 * 16 * TPS];
    const int tid = threadIdx.x, w = tid >> 6, ln = tid & 63;
    const int quad = ln >> 4, lr = ln & 15;
    const int m0 = blockIdx.x * 16;

    // GEMM1: V = X[rows,:] * M   (A from global X planes)
    float4v acc[8], a2[8];
    #pragma unroll
    for (int ct = 0; ct < 8; ++ct) { acc[ct] = (float4v){0.f,0.f,0.f,0.f}; a2[ct] = acc[ct]; }
    for (int kw = 0; kw < 16; ++kw) {
        int ko = kw * 32 + quad * 8;
        short8 ah = *(const short8*)(Xh + (size_t)(m0 + lr) * 512 + ko);
        short8 al = *(const short8*)(Xl + (size_t)(m0 + lr) * 512 + ko);
        #pragma unroll
        for (int ct = 0; ct < 8; ++ct) {
            size_t bo = (size_t)(w * 128 + ct * 16 + lr) * 512 + ko;
            short8 bh = *(const short8*)(Mh + bo);
            short8 bl = *(const short8*)(Ml + bo);
            acc[ct] = __builtin_amdgcn_mfma_f32_16x16x32_bf16(ah, bh, acc[ct], 0, 0, 0);
            a2[ct]  = __builtin_amdgcn_mfma_f32_16x16x32_bf16(ah, bl, a2[ct], 0, 0, 0);
            a2[ct]  = __builtin_amdgcn_mfma_f32_16x16x32_bf16(al, bh, a2[ct], 0, 0, 0);
        }
    }
    #pragma unroll
    for (int ct = 0; ct < 8; ++ct) {
        float4v v = acc[ct] + a2[ct];
        #pragma unroll
        for (int r = 0; r < 4; ++r) split_lds(v[r], tp, quad * 4 + r, w * 128 + ct * 16 + lr);
    }
    __syncthreads();
    // GEMM2: out = V * X  (A from LDS, B = X planes); X' = 2X - out
    row_gemm(Xh, Xl, tp, w, quad, lr, acc);
    #pragma unroll
    for (int ct = 0; ct < 8; ++ct) {
        #pragma unroll
        for (int r = 0; r < 4; ++r) {
            int m = m0 + quad * 4 + r, n = w * 128 + ct * 16 + lr;
            size_t idx = (size_t)m * 512 + n;
            float v = 2.f * Xf[idx] - acc[ct][r];
            Xnf[idx] = v;
            split_store(v, Xnh, Xnl, idx);
        }
    }
}

// ---------------- skinny ME-dim kernels (round-6 verified) ----------------
__global__ void Y_k(const float* __restrict__ Minv, const float* __restrict__ AF,
                    float* __restrict__ Y) {
    int m = blockIdx.x;
    int wv = threadIdx.x >> 6, lane = threadIdx.x & 63;
    float mv[8];
    #pragma unroll
    for (int i = 0; i < 8; ++i) mv[i] = Minv[m * 512 + lane + i * 64];
    #pragma unroll
    for (int jj = 0; jj < 4; ++jj) {
        int j = wv * 4 + jj;
        float s = 0.f;
        #pragma unroll
        for (int i = 0; i < 8; ++i) s += mv[i] * AF[j * 512 + lane + i * 64];
        for (int off = 32; off; off >>= 1) s += __shfl_down(s, off);
        if (lane == 0) Y[m * 16 + j] = s;
    }
}

__global__ void Sm_k(const float* __restrict__ AF, const float* __restrict__ Y,
                     float* __restrict__ Sm) {
    int i = threadIdx.x >> 4, j = threadIdx.x & 15;
    float s = 0.f;
    #pragma unroll 8
    for (int k = 0; k < 512; ++k) s += AF[i * 512 + k] * Y[k * 16 + j];
    Sm[i * 16 + j] = s;
}

__global__ void inv16_k(const float* __restrict__ S, float* __restrict__ Si) {
    int r = threadIdx.x;
    float a[16], bI[16];
    #pragma unroll
    for (int j = 0; j < 16; ++j) {
        a[j]  = (r < 16) ? S[r * 16 + j] : 0.f;
        bI[j] = (r < 16 && j == r) ? 1.f : 0.f;
    }
    for (int k = 0; k < 16; ++k) {
        float pa[16], pb[16];
        #pragma unroll
        for (int j = 0; j < 16; ++j) { pa[j] = __shfl(a[j], k); pb[j] = __shfl(bI[j], k); }
        float inv = 1.0f / pa[k];
        if (r == k) {
            #pragma unroll
            for (int j = 0; j < 16; ++j) { a[j] = pa[j] * inv; bI[j] = pb[j] * inv; }
        } else {
            float f = a[k] * inv;
            #pragma unroll
            for (int j = 0; j < 16; ++j) {
                a[j]  = fmaf(-f, pa[j], a[j]);
                bI[j] = fmaf(-f, pb[j], bI[j]);
            }
        }
    }
    if (r < 16)
        #pragma unroll
        for (int j = 0; j < 16; ++j) Si[r * 16 + j] = bI[j];
}

__global__ void T1zb_k(const float* __restrict__ Y, const float* __restrict__ Si,
                       const float* __restrict__ bF, float* __restrict__ T1,
                       float* __restrict__ zb) {
    int m = blockIdx.x * 16 + (threadIdx.x >> 4), j = threadIdx.x & 15;
    float s = 0.f;
    #pragma unroll
    for (int k = 0; k < 16; ++k) s += Y[m * 16 + k] * Si[k * 16 + j];
    T1[m * 16 + j] = s;
    float v = s * bF[j];
    v += __shfl_down(v, 8); v += __shfl_down(v, 4);
    v += __shfl_down(v, 2); v += __shfl_down(v, 1);
    if (j == 0) zb[m] = v;
}

__global__ void W1_k(const float* __restrict__ Minv, const float* __restrict__ T1,
                     const float* __restrict__ Y,
                     short* __restrict__ W1h, short* __restrict__ W1l) {
    int idx = blockIdx.x * 256 + threadIdx.x;
    int m = idx >> 9, n = idx & 511;
    float s = Minv[idx];
    #pragma unroll
    for (int k = 0; k < 16; ++k) s -= T1[m * 16 + k] * Y[n * 16 + k];
    split_store(s, W1h, W1l, idx);
}

__global__ void g0_k(const float* __restrict__ GF, const float* __restrict__ zb,
                     float* __restrict__ g0) {
    int m = blockIdx.x * 4 + (threadIdx.x >> 6);
    int lane = threadIdx.x & 63;
    float s = 0.f;
    #pragma unroll
    for (int i = 0; i < 8; ++i) s += GF[m * 512 + lane + i * 64] * zb[lane + i * 64];
    for (int off = 32; off; off >>= 1) s += __shfl_down(s, off);
    if (lane == 0) g0[m] = s;
}

// ---------------- row-local projection kernel: the entire PGD pipeline -------
// 64 blocks x 16 batch rows. Zero grid syncs: the batch dimension is
// embarrassingly parallel through combo/ADMM/final-z/PGD. t,u,q0,xW live in
// registers; t/x planes round-trip through LDS; Q/R/W1/G/RT stream from L2.
struct PArgs {
    const short *Gh, *Gl, *Rh, *Rl, *Wh, *Wl, *Qh, *Ql, *RTh, *RTl;
    const short *xh, *xl;
    const float *hF, *g0, *zb, *cF, *dtf;
    void* Out;
};

__global__ __launch_bounds__(256, 1) void proj_row_k(PArgs a) {
    __shared__ short tp[2 * 16 * TPS];
    const int tid = threadIdx.x, w = tid >> 6, ln = tid & 63;
    const int quad = ln >> 4, lr = ln & 15;
    const int m0 = blockIdx.x * 16;

    float hreg[8], g0r[8], zbr[8];
    #pragma unroll
    for (int ct = 0; ct < 8; ++ct) {
        int n = w * 128 + ct * 16 + lr;
        hreg[ct] = a.hF[n];
        g0r[ct]  = a.g0[n];
        zbr[ct]  = a.zb[n];
    }
    float dtfv = a.dtf[0];

    // load x0 = c planes into LDS
    #pragma unroll
    for (int i = 0; i < 4; ++i) {
        int v = tid + 256 * i;
        int row = v >> 6, oct = v & 63;
        *(short8*)&tp[row * TPS + oct * 8] =
            *(const short8*)(a.xh + (size_t)(m0 + row) * 512 + oct * 8);
        *(short8*)&tp[TPP + row * TPS + oct * 8] =
            *(const short8*)(a.xl + (size_t)(m0 + row) * 512 + oct * 8);
    }
    __syncthreads();

    float4v q0r[8], xWr[8], u4[8], acc[8];

    for (int p = 0; p < 4; ++p) {
        // combo sub1: q0 = x R^T + g0
        row_gemm(a.Rh, a.Rl, tp, w, quad, lr, acc);
        #pragma unroll
        for (int ct = 0; ct < 8; ++ct)
            #pragma unroll
            for (int r = 0; r < 4; ++r) q0r[ct][r] = acc[ct][r] + g0r[ct];
        // combo sub2: xW = x W1
        row_gemm(a.Wh, a.Wl, tp, w, quad, lr, acc);
        #pragma unroll
        for (int ct = 0; ct < 8; ++ct) xWr[ct] = acc[ct];
        // combo sub3: t0 = min(h, x G^T), u0 = 0  (overwrite x planes with t0)
        row_gemm(a.Gh, a.Gl, tp, w, quad, lr, acc);
        __syncthreads();
        #pragma unroll
        for (int ct = 0; ct < 8; ++ct) {
            int n = w * 128 + ct * 16 + lr;
            #pragma unroll
            for (int r = 0; r < 4; ++r) {
                u4[ct][r] = 0.f;
                split_lds(fminf(hreg[ct], acc[ct][r]), tp, quad * 4 + r, n);
            }
        }
        __syncthreads();

        // 15 ADMM iterations, all in-block
        for (int it = 0; it < ADMM_IT; ++it) {
            row_gemm(a.Qh, a.Ql, tp, w, quad, lr, acc);
            __syncthreads();
            #pragma unroll
            for (int ct = 0; ct < 8; ++ct) {
                int n = w * 128 + ct * 16 + lr;
                #pragma unroll
                for (int r = 0; r < 4; ++r) {
                    float gz = acc[ct][r] + q0r[ct][r];
                    float wv = hreg[ct] - gz - u4[ct][r];
                    u4[ct][r] = fmaxf(0.f, -wv);
                    split_lds(hreg[ct] - fabsf(wv), tp, quad * 4 + r, n);
                }
            }
            __syncthreads();
        }

        // final z = t R + xW + zb; then PGD (write x' planes) or emit
        row_gemm(a.RTh, a.RTl, tp, w, quad, lr, acc);
        if (p < 3) {
            __syncthreads();
            #pragma unroll
            for (int ct = 0; ct < 8; ++ct) {
                int n = w * 128 + ct * 16 + lr;
                #pragma unroll
                for (int r = 0; r < 4; ++r) {
                    int m = m0 + quad * 4 + r;
                    float z = acc[ct][r] + xWr[ct][r] + zbr[ct];
                    float xv = (1.0f - ALPHA) * z + ALPHA * a.cF[(size_t)m * 512 + n];
                    split_lds(xv, tp, quad * 4 + r, n);
                }
            }
            __syncthreads();
        } else {
            #pragma unroll
            for (int ct = 0; ct < 8; ++ct) {
                int n = w * 128 + ct * 16 + lr;
                #pragma unroll
                for (int r = 0; r < 4; ++r) {
                    int m = m0 + quad * 4 + r;
                    size_t idx = (size_t)m * 512 + n;
                    float z = acc[ct][r] + xWr[ct][r] + zbr[ct];
                    if (dtfv > 0.5f) ((__hip_bfloat16*)a.Out)[idx] = __float2bfloat16(z);
                    else             ((float*)a.Out)[idx] = z;
                }
            }
        }
    }
}

// ---------------- host launcher ----------------

extern "C" void kernel_launch(void* const* d_in, const int* in_sizes, int n_in,
                              void* d_out, int out_size, void* d_ws, size_t ws_size,
                              hipStream_t stream) {
    const void* c_raw = d_in[0];
    const void* G_raw = d_in[1];
    const void* h_raw = d_in[2];
    const void* A_raw = d_in[3];
    const void* b_raw = d_in[4];

    float* w = (float*)d_ws;
    size_t o = 0;
    auto alloc = [&](size_t n) { float* p = w + o; o += (n + 63) & ~(size_t)63; return p; };

    float* cF  = alloc(BB * NN);
    float* GF  = alloc(MI * NN);
    float* AF  = alloc(ME * NN);
    float* hF  = alloc(MI);
    float* bF  = alloc(ME);
    float* Mm  = alloc(NN * NN);
    float* Xf0 = alloc(NN * NN);
    float* Xf1 = alloc(NN * NN);
    float* Rf  = alloc(MI * NN);
    float* Y   = alloc(NN * ME);
    float* T1  = alloc(NN * ME);
    float* Sm  = alloc(ME * ME);
    float* Si  = alloc(ME * ME);
    float* zb  = alloc(NN);
    float* g0  = alloc(MI);
    float* rs  = alloc(NN);
    float* dtf = alloc(16);

    short* sbp = (short*)(w + o);
    size_t so = 0;
    auto allocS = [&](size_t n) { short* p = sbp + so; so += (n + 127) & ~(size_t)127; return p; };

    short* GFh = allocS(MI * NN);  short* GFl = allocS(MI * NN);
    short* GTh = allocS(NN * MI);  short* GTl = allocS(NN * MI);
    short* Mmh = allocS(NN * NN);  short* Mml = allocS(NN * NN);
    short* X0h = allocS(NN * NN);  short* X0l = allocS(NN * NN);
    short* X1h = allocS(NN * NN);  short* X1l = allocS(NN * NN);
    short* W1h = allocS(NN * NN);  short* W1l = allocS(NN * NN);
    short* Rh  = allocS(MI * NN);  short* Rl  = allocS(MI * NN);
    short* RTh = allocS(NN * MI);  short* RTl = allocS(NN * MI);
    short* Qh  = allocS(MI * MI);  short* Ql  = allocS(MI * MI);
    short* xh  = allocS(BB * NN);  short* xl  = allocS(BB * NN);

    dim3 blk(256);
    auto cdiv = [](int a, int b) { return (a + b - 1) / b; };
    dim3 gSq(8, 32);

    detect_dtype_k<<<1, 256, 0, stream>>>((const unsigned short*)G_raw, dtf);
    ingest_all_k<<<cdiv(BB * NN, 256), blk, 0, stream>>>(
        c_raw, G_raw, h_raw, A_raw, b_raw,
        cF, xh, xl, GF, GFh, GFl, hF, AF, bF, rs, dtf);
    transpose_split_k<<<dim3(16, 16), blk, 0, stream>>>(GF, GTh, GTl);

    // M = I + G^T G  (f32 + planes + row-abs-sum atomics)
    gemm16_k<<<gSq, blk, 0, stream>>>(GTh, GTl, GTh, GTl, Mm, Mmh, Mml, rs, 1);
    // X0 = c0 I
    initX_k<<<256, blk, 0, stream>>>(rs, Xf0, X0h, X0l);

    // Newton-Schulz: 8 fused double-GEMM launches (row-local via symmetry)
    float* Xf[2] = {Xf0, Xf1};
    short* Xh[2] = {X0h, X1h};
    short* Xl[2] = {X0l, X1l};
    int cur = 0;
    for (int it = 0; it < NS_ITERS; ++it) {
        int nxt = cur ^ 1;
        ns_pair_k<<<32, blk, 0, stream>>>(Xh[cur], Xl[cur], Xf[cur], Mmh, Mml,
                                          Xf[nxt], Xh[nxt], Xl[nxt]);
        cur = nxt;
    }
    float* Minv = Xf[cur];  // cur == 0 for even NS_ITERS

    // Schur pieces
    Y_k<<<NN, blk, 0, stream>>>(Minv, AF, Y);
    Sm_k<<<1, blk, 0, stream>>>(AF, Y, Sm);
    inv16_k<<<1, 64, 0, stream>>>(Sm, Si);
    T1zb_k<<<NN / 16, blk, 0, stream>>>(Y, Si, bF, T1, zb);
    W1_k<<<NN * NN / 256, blk, 0, stream>>>(Minv, T1, Y, W1h, W1l);

    // R = G W1 (f32 + planes), RT planes, Q = R G^T (planes), g0
    gemm16_k<<<gSq, blk, 0, stream>>>(GFh, GFl, W1h, W1l, Rf, Rh, Rl, nullptr, 0);
    transpose_split_k<<<dim3(16, 16), blk, 0, stream>>>(Rf, RTh, RTl);
    gemm16_k<<<gSq, blk, 0, stream>>>(Rh, Rl, GFh, GFl, nullptr, Qh, Ql, nullptr, 9);
    g0_k<<<NN / 4, blk, 0, stream>>>(GF, zb, g0);

    // the whole 4-projection PGD pipeline: one launch, zero grid syncs
    PArgs pa;
    pa.Gh = GFh; pa.Gl = GFl; pa.Rh = Rh; pa.Rl = Rl; pa.Wh = W1h; pa.Wl = W1l;
    pa.Qh = Qh; pa.Ql = Ql; pa.RTh = RTh; pa.RTl = RTl;
    pa.xh = xh; pa.xl = xl;
    pa.hF = hF; pa.g0 = g0; pa.zb = zb; pa.cF = cF; pa.dtf = dtf;
    pa.Out = d_out;
    proj_row_k<<<64, blk, 0, stream>>>(pa);
}

// Round 10
// 2880.636 us; speedup vs baseline: 1.0705x; 1.0705x over previous
//
#include <hip/hip_runtime.h>
#include <hip/hip_bf16.h>

// Problem constants (fixed by the reference)
#define BB 1024
#define NN 512
#define MI 512
#define ME 16
#define ALPHA 0.05f
#define NS_ITERS 8   // Gershgorin c0 -> r~0.9; 0.9^256 ~ 7e-12: converged
#define ADMM_IT 15

typedef __attribute__((ext_vector_type(8))) short short8;
typedef __attribute__((ext_vector_type(4))) float float4v;

__device__ inline short f2bf(float v) {
    __hip_bfloat16 b = __float2bfloat16(v);
    return *reinterpret_cast<short*>(&b);
}
__device__ inline float bf2f(short s) {
    __hip_bfloat16 b = *reinterpret_cast<__hip_bfloat16*>(&s);
    return __bfloat162float(b);
}
__device__ inline void split_store(float v, short* __restrict__ hi, short* __restrict__ lo, size_t idx) {
    short h = f2bf(v);
    hi[idx] = h;
    lo[idx] = f2bf(v - bf2f(h));
}

// ---------------- dtype auto-detect ----------------
__global__ void detect_dtype_k(const unsigned short* __restrict__ g_raw,
                               float* __restrict__ flag) {
    __shared__ int cnt;
    int tid = threadIdx.x;
    if (tid == 0) cnt = 0;
    __syncthreads();
    int local = 0;
    for (int i = tid; i < 8192; i += 256) {
        int e = (g_raw[i] >> 7) & 0xFF;
        if (e >= 0x83) local++;
    }
    atomicAdd(&cnt, local);
    __syncthreads();
    if (tid == 0) flag[0] = (cnt < 64) ? 1.0f : 0.0f;  // 1 => bf16 inputs
}

// ---------------- fused ingest (also zeroes rs accumulator) ----------------
__global__ void ingest_all_k(const void* __restrict__ c_raw, const void* __restrict__ G_raw,
                             const void* __restrict__ h_raw, const void* __restrict__ A_raw,
                             const void* __restrict__ b_raw,
                             float* __restrict__ cF, short* __restrict__ xh, short* __restrict__ xl,
                             float* __restrict__ GF, short* __restrict__ GFh, short* __restrict__ GFl,
                             float* __restrict__ hF, float* __restrict__ AF, float* __restrict__ bF,
                             float* __restrict__ rs, const float* __restrict__ flag) {
    int i = blockIdx.x * 256 + threadIdx.x;
    bool isbf = flag[0] > 0.5f;
    #define RD(p, idx) (isbf ? __bfloat162float(((const __hip_bfloat16*)(p))[idx]) : ((const float*)(p))[idx])
    if (i < BB * NN) { float v = RD(c_raw, i); cF[i] = v; split_store(v, xh, xl, i); }
    if (i < MI * NN) { float v = RD(G_raw, i); GF[i] = v; split_store(v, GFh, GFl, i); }
    if (i < MI)      hF[i] = RD(h_raw, i);
    if (i < ME * NN) AF[i] = RD(A_raw, i);
    if (i < ME)      bF[i] = RD(b_raw, i);
    if (i < NN)      rs[i] = 0.f;
    #undef RD
}

// transpose 512x512 f32 -> bf16 hi/lo planes
__global__ void transpose_split_k(const float* __restrict__ src,
                                  short* __restrict__ dh, short* __restrict__ dl) {
    __shared__ float t[32][33];
    int bx = blockIdx.x * 32, by = blockIdx.y * 32;
    int tx = threadIdx.x & 31, ty0 = threadIdx.x >> 5;
    for (int i = ty0; i < 32; i += 8) t[i][tx] = src[(by + i) * 512 + bx + tx];
    __syncthreads();
    for (int i = ty0; i < 32; i += 8)
        split_store(t[tx][i], dh, dl, (size_t)(bx + i) * 512 + by + tx);
}

// ---------------- LDS-staged 16x64 tile GEMM (K=512), precompute only ---------
#define CH 128
#define LDC 136

__device__ __forceinline__ void tile16(
    const short* __restrict__ Ahi, const short* __restrict__ Alo,
    const short* __restrict__ Bhi, const short* __restrict__ Blo,
    int m0, int n0, short* __restrict__ As, short* __restrict__ Bs,
    float4v* __restrict__ out)
{
    const int tid = threadIdx.x;
    const int wv = tid >> 6, ln = tid & 63;
    const int quad = ln >> 4, lr = ln & 15;

    float4v acc1 = {0.f,0.f,0.f,0.f}, acc2 = {0.f,0.f,0.f,0.f};

    short8 pa[2], pb[8];
    #pragma unroll
    for (int i = 0; i < 2; ++i) {
        int s = tid + 256 * i; int pl = s >> 8, rem = s & 255, row = rem >> 4, oct = rem & 15;
        const short* P = pl ? Alo : Ahi;
        pa[i] = *(const short8*)(P + (size_t)(m0 + row) * 512 + oct * 8);
    }
    #pragma unroll
    for (int i = 0; i < 8; ++i) {
        int s = tid + 256 * i; int pl = s >> 10, rem = s & 1023, row = rem >> 4, oct = rem & 15;
        const short* P = pl ? Blo : Bhi;
        pb[i] = *(const short8*)(P + (size_t)(n0 + row) * 512 + oct * 8);
    }

    for (int c = 0; c < 4; ++c) {
        __syncthreads();
        #pragma unroll
        for (int i = 0; i < 2; ++i) {
            int s = tid + 256 * i; int pl = s >> 8, rem = s & 255, row = rem >> 4, oct = rem & 15;
            *(short8*)&As[pl * (16 * LDC) + row * LDC + oct * 8] = pa[i];
        }
        #pragma unroll
        for (int i = 0; i < 8; ++i) {
            int s = tid + 256 * i; int pl = s >> 10, rem = s & 1023, row = rem >> 4, oct = rem & 15;
            *(short8*)&Bs[pl * (64 * LDC) + row * LDC + oct * 8] = pb[i];
        }
        __syncthreads();
        if (c + 1 < 4) {
            int kb = (c + 1) * CH;
            #pragma unroll
            for (int i = 0; i < 2; ++i) {
                int s = tid + 256 * i; int pl = s >> 8, rem = s & 255, row = rem >> 4, oct = rem & 15;
                const short* P = pl ? Alo : Ahi;
                pa[i] = *(const short8*)(P + (size_t)(m0 + row) * 512 + kb + oct * 8);
            }
            #pragma unroll
            for (int i = 0; i < 8; ++i) {
                int s = tid + 256 * i; int pl = s >> 10, rem = s & 1023, row = rem >> 4, oct = rem & 15;
                const short* P = pl ? Blo : Bhi;
                pb[i] = *(const short8*)(P + (size_t)(n0 + row) * 512 + kb + oct * 8);
            }
        }
        #pragma unroll
        for (int ks = 0; ks < 4; ++ks) {
            int ko = (ks * 4 + quad) * 8;
            short8 ah = *(const short8*)&As[lr * LDC + ko];
            short8 al = *(const short8*)&As[16 * LDC + lr * LDC + ko];
            short8 bh = *(const short8*)&Bs[(wv * 16 + lr) * LDC + ko];
            short8 bl = *(const short8*)&Bs[64 * LDC + (wv * 16 + lr) * LDC + ko];
            acc1 = __builtin_amdgcn_mfma_f32_16x16x32_bf16(ah, bh, acc1, 0, 0, 0);
            acc2 = __builtin_amdgcn_mfma_f32_16x16x32_bf16(ah, bl, acc2, 0, 0, 0);
            acc2 = __builtin_amdgcn_mfma_f32_16x16x32_bf16(al, bh, acc2, 0, 0, 0);
        }
    }
    out[0] = acc1 + acc2;
}

// epi: 0 = f32 + planes; 1 = +I, f32 + planes, rs row-abs atomics; 9 = planes only
__global__ __launch_bounds__(256) void gemm16_k(
    const short* __restrict__ Ahi, const short* __restrict__ Alo,
    const short* __restrict__ Bhi, const short* __restrict__ Blo,
    float* __restrict__ C, short* __restrict__ Chi, short* __restrict__ Clo,
    float* __restrict__ rs, int epi)
{
    __shared__ short smem[2 * 16 * LDC + 2 * 64 * LDC];
    short* As = smem;
    short* Bs = smem + 2 * 16 * LDC;
    int m0 = blockIdx.y * 16, n0 = blockIdx.x * 64;
    float4v out[1];
    tile16(Ahi, Alo, Bhi, Blo, m0, n0, As, Bs, out);
    int ln = threadIdx.x & 63, wv = threadIdx.x >> 6;
    int quad = ln >> 4, lr = ln & 15;
    #pragma unroll
    for (int r = 0; r < 4; ++r) {
        int m = m0 + quad * 4 + r, n = n0 + wv * 16 + lr;
        size_t idx = (size_t)m * 512 + n;
        float v = out[0][r];
        if (epi == 1) v += (m == n) ? 1.f : 0.f;
        if (epi != 9) C[idx] = v;
        split_store(v, Chi, Clo, idx);
        if (epi == 1) {
            float s = fabsf(v);
            s += __shfl_xor(s, 1); s += __shfl_xor(s, 2);
            s += __shfl_xor(s, 4); s += __shfl_xor(s, 8);
            if (lr == 0) atomicAdd(&rs[m], s);
        }
    }
}

// X0 = c0 * I with c0 = 2/(1+max rs)
__global__ void initX_k(const float* __restrict__ rs, float* __restrict__ X,
                        short* __restrict__ Xh, short* __restrict__ Xl) {
    int ln = threadIdx.x & 63;
    float mx = 0.f;
    #pragma unroll
    for (int i = 0; i < 8; ++i) mx = fmaxf(mx, rs[ln + i * 64]);
    for (int off = 32; off; off >>= 1) mx = fmaxf(mx, __shfl_down(mx, off));
    float c0 = 2.0f / (1.0f + __shfl(mx, 0));
    #pragma unroll
    for (int j = 0; j < 4; ++j) {
        int idx = blockIdx.x * 1024 + j * 256 + threadIdx.x;
        int r = idx >> 9, cc = idx & 511;
        float v = (r == cc) ? c0 : 0.f;
        X[idx] = v;
        split_store(v, Xh, Xl, idx);
    }
}

// ---------------- row-local sweeps, 1024-thread blocks (16 waves) ------------
// Wave w (0..15) owns cols n = w*32 + ct*16 + lr (ct = 0,1). 16 rows per block.
// B fragments stream from L2 with register double-buffering; 4 waves/SIMD TLP
// hides the remaining latency (round-9's 1 wave/SIMD was the regression).
#define TPS 520
#define TPP (16 * TPS)

__device__ __forceinline__ void row_sweep_lds(
    const short* __restrict__ Bh, const short* __restrict__ Bl,
    const short* __restrict__ tp, int w, int quad, int lr,
    float4v* __restrict__ acc)
{
    float4v a2[2];
    acc[0] = (float4v){0.f,0.f,0.f,0.f}; acc[1] = acc[0];
    a2[0] = acc[0]; a2[1] = acc[0];
    const size_t bo0 = (size_t)(w * 32 + lr) * 512;
    const size_t bo1 = bo0 + 16 * 512;
    short8 b0h = *(const short8*)(Bh + bo0 + quad * 8);
    short8 b0l = *(const short8*)(Bl + bo0 + quad * 8);
    short8 b1h = *(const short8*)(Bh + bo1 + quad * 8);
    short8 b1l = *(const short8*)(Bl + bo1 + quad * 8);
    #pragma unroll
    for (int kw = 0; kw < 16; ++kw) {
        short8 c0h = b0h, c0l = b0l, c1h = b1h, c1l = b1l;
        if (kw < 15) {
            int nko = (kw + 1) * 32 + quad * 8;
            b0h = *(const short8*)(Bh + bo0 + nko);
            b0l = *(const short8*)(Bl + bo0 + nko);
            b1h = *(const short8*)(Bh + bo1 + nko);
            b1l = *(const short8*)(Bl + bo1 + nko);
        }
        int ao = kw * 32 + quad * 8;
        short8 ah = *(const short8*)&tp[lr * TPS + ao];
        short8 al = *(const short8*)&tp[TPP + lr * TPS + ao];
        acc[0] = __builtin_amdgcn_mfma_f32_16x16x32_bf16(ah, c0h, acc[0], 0, 0, 0);
        a2[0]  = __builtin_amdgcn_mfma_f32_16x16x32_bf16(ah, c0l, a2[0], 0, 0, 0);
        a2[0]  = __builtin_amdgcn_mfma_f32_16x16x32_bf16(al, c0h, a2[0], 0, 0, 0);
        acc[1] = __builtin_amdgcn_mfma_f32_16x16x32_bf16(ah, c1h, acc[1], 0, 0, 0);
        a2[1]  = __builtin_amdgcn_mfma_f32_16x16x32_bf16(ah, c1l, a2[1], 0, 0, 0);
        a2[1]  = __builtin_amdgcn_mfma_f32_16x16x32_bf16(al, c1h, a2[1], 0, 0, 0);
    }
    acc[0] = acc[0] + a2[0];
    acc[1] = acc[1] + a2[1];
}

__device__ __forceinline__ void row_sweep_glb(
    const short* __restrict__ Ah, const short* __restrict__ Al, int m0,
    const short* __restrict__ Bh, const short* __restrict__ Bl,
    int w, int quad, int lr, float4v* __restrict__ acc)
{
    float4v a2[2];
    acc[0] = (float4v){0.f,0.f,0.f,0.f}; acc[1] = acc[0];
    a2[0] = acc[0]; a2[1] = acc[0];
    const size_t ao0 = (size_t)(m0 + lr) * 512;
    const size_t bo0 = (size_t)(w * 32 + lr) * 512;
    const size_t bo1 = bo0 + 16 * 512;
    short8 rah = *(const short8*)(Ah + ao0 + quad * 8);
    short8 ral = *(const short8*)(Al + ao0 + quad * 8);
    short8 b0h = *(const short8*)(Bh + bo0 + quad * 8);
    short8 b0l = *(const short8*)(Bl + bo0 + quad * 8);
    short8 b1h = *(const short8*)(Bh + bo1 + quad * 8);
    short8 b1l = *(const short8*)(Bl + bo1 + quad * 8);
    #pragma unroll
    for (int kw = 0; kw < 16; ++kw) {
        short8 ah = rah, al = ral;
        short8 c0h = b0h, c0l = b0l, c1h = b1h, c1l = b1l;
        if (kw < 15) {
            int nko = (kw + 1) * 32 + quad * 8;
            rah = *(const short8*)(Ah + ao0 + nko);
            ral = *(const short8*)(Al + ao0 + nko);
            b0h = *(const short8*)(Bh + bo0 + nko);
            b0l = *(const short8*)(Bl + bo0 + nko);
            b1h = *(const short8*)(Bh + bo1 + nko);
            b1l = *(const short8*)(Bl + bo1 + nko);
        }
        acc[0] = __builtin_amdgcn_mfma_f32_16x16x32_bf16(ah, c0h, acc[0], 0, 0, 0);
        a2[0]  = __builtin_amdgcn_mfma_f32_16x16x32_bf16(ah, c0l, a2[0], 0, 0, 0);
        a2[0]  = __builtin_amdgcn_mfma_f32_16x16x32_bf16(al, c0h, a2[0], 0, 0, 0);
        acc[1] = __builtin_amdgcn_mfma_f32_16x16x32_bf16(ah, c1h, acc[1], 0, 0, 0);
        a2[1]  = __builtin_amdgcn_mfma_f32_16x16x32_bf16(ah, c1l, a2[1], 0, 0, 0);
        a2[1]  = __builtin_amdgcn_mfma_f32_16x16x32_bf16(al, c1h, a2[1], 0, 0, 0);
    }
    acc[0] = acc[0] + a2[0];
    acc[1] = acc[1] + a2[1];
}

__device__ __forceinline__ void split_lds(float v, short* __restrict__ tp, int ml, int n) {
    short h = f2bf(v);
    tp[ml * TPS + n] = h;
    tp[TPP + ml * TPS + n] = f2bf(v - bf2f(h));
}

// ---------------- NS pair kernel: X' = 2X - (X M) X, 32 blocks x 1024 --------
__global__ __launch_bounds__(1024, 1) void ns_pair2_k(
    const short* __restrict__ Xh, const short* __restrict__ Xl, const float* __restrict__ Xf,
    const short* __restrict__ Mh, const short* __restrict__ Ml,
    float* __restrict__ Xnf, short* __restrict__ Xnh, short* __restrict__ Xnl)
{
    __shared__ short tp[2 * TPP];
    const int tid = threadIdx.x, w = tid >> 6, ln = tid & 63;
    const int quad = ln >> 4, lr = ln & 15;
    const int m0 = blockIdx.x * 16;
    float4v acc[2];

    // GEMM1: V = X[rows m0..m0+15] * M   (A, B from global planes)
    row_sweep_glb(Xh, Xl, m0, Mh, Ml, w, quad, lr, acc);
    #pragma unroll
    for (int ct = 0; ct < 2; ++ct)
        #pragma unroll
        for (int r = 0; r < 4; ++r)
            split_lds(acc[ct][r], tp, quad * 4 + r, w * 32 + ct * 16 + lr);
    __syncthreads();
    // GEMM2: out = V * X (A from LDS, X symmetric); X' = 2X - out
    row_sweep_lds(Xh, Xl, tp, w, quad, lr, acc);
    #pragma unroll
    for (int ct = 0; ct < 2; ++ct) {
        #pragma unroll
        for (int r = 0; r < 4; ++r) {
            int m = m0 + quad * 4 + r, n = w * 32 + ct * 16 + lr;
            size_t idx = (size_t)m * 512 + n;
            float v = 2.f * Xf[idx] - acc[ct][r];
            Xnf[idx] = v;
            split_store(v, Xnh, Xnl, idx);
        }
    }
}

// ---------------- skinny ME-dim kernels ----------------
__global__ void Y_k(const float* __restrict__ Minv, const float* __restrict__ AF,
                    float* __restrict__ Y) {
    int m = blockIdx.x;
    int wv = threadIdx.x >> 6, lane = threadIdx.x & 63;
    float mv[8];
    #pragma unroll
    for (int i = 0; i < 8; ++i) mv[i] = Minv[m * 512 + lane + i * 64];
    #pragma unroll
    for (int jj = 0; jj < 4; ++jj) {
        int j = wv * 4 + jj;
        float s = 0.f;
        #pragma unroll
        for (int i = 0; i < 8; ++i) s += mv[i] * AF[j * 512 + lane + i * 64];
        for (int off = 32; off; off >>= 1) s += __shfl_down(s, off);
        if (lane == 0) Y[m * 16 + j] = s;
    }
}

__global__ void Sm_k(const float* __restrict__ AF, const float* __restrict__ Y,
                     float* __restrict__ Sm) {
    int i = threadIdx.x >> 4, j = threadIdx.x & 15;
    float s = 0.f;
    #pragma unroll 8
    for (int k = 0; k < 512; ++k) s += AF[i * 512 + k] * Y[k * 16 + j];
    Sm[i * 16 + j] = s;
}

__global__ void inv16_k(const float* __restrict__ S, float* __restrict__ Si) {
    int r = threadIdx.x;
    float a[16], bI[16];
    #pragma unroll
    for (int j = 0; j < 16; ++j) {
        a[j]  = (r < 16) ? S[r * 16 + j] : 0.f;
        bI[j] = (r < 16 && j == r) ? 1.f : 0.f;
    }
    for (int k = 0; k < 16; ++k) {
        float pa[16], pb[16];
        #pragma unroll
        for (int j = 0; j < 16; ++j) { pa[j] = __shfl(a[j], k); pb[j] = __shfl(bI[j], k); }
        float inv = 1.0f / pa[k];
        if (r == k) {
            #pragma unroll
            for (int j = 0; j < 16; ++j) { a[j] = pa[j] * inv; bI[j] = pb[j] * inv; }
        } else {
            float f = a[k] * inv;
            #pragma unroll
            for (int j = 0; j < 16; ++j) {
                a[j]  = fmaf(-f, pa[j], a[j]);
                bI[j] = fmaf(-f, pb[j], bI[j]);
            }
        }
    }
    if (r < 16)
        #pragma unroll
        for (int j = 0; j < 16; ++j) Si[r * 16 + j] = bI[j];
}

__global__ void T1zb_k(const float* __restrict__ Y, const float* __restrict__ Si,
                       const float* __restrict__ bF, float* __restrict__ T1,
                       float* __restrict__ zb) {
    int m = blockIdx.x * 16 + (threadIdx.x >> 4), j = threadIdx.x & 15;
    float s = 0.f;
    #pragma unroll
    for (int k = 0; k < 16; ++k) s += Y[m * 16 + k] * Si[k * 16 + j];
    T1[m * 16 + j] = s;
    float v = s * bF[j];
    v += __shfl_down(v, 8); v += __shfl_down(v, 4);
    v += __shfl_down(v, 2); v += __shfl_down(v, 1);
    if (j == 0) zb[m] = v;
}

__global__ void W1_k(const float* __restrict__ Minv, const float* __restrict__ T1,
                     const float* __restrict__ Y,
                     short* __restrict__ W1h, short* __restrict__ W1l) {
    int idx = blockIdx.x * 256 + threadIdx.x;
    int m = idx >> 9, n = idx & 511;
    float s = Minv[idx];
    #pragma unroll
    for (int k = 0; k < 16; ++k) s -= T1[m * 16 + k] * Y[n * 16 + k];
    split_store(s, W1h, W1l, idx);
}

__global__ void g0_k(const float* __restrict__ GF, const float* __restrict__ zb,
                     float* __restrict__ g0) {
    int m = blockIdx.x * 4 + (threadIdx.x >> 6);
    int lane = threadIdx.x & 63;
    float s = 0.f;
    #pragma unroll
    for (int i = 0; i < 8; ++i) s += GF[m * 512 + lane + i * 64] * zb[lane + i * 64];
    for (int off = 32; off; off >>= 1) s += __shfl_down(s, off);
    if (lane == 0) g0[m] = s;
}

// ---------------- row-local projection kernel, 64 blocks x 1024 --------------
struct PArgs {
    const short *Gh, *Gl, *Rh, *Rl, *Wh, *Wl, *Qh, *Ql, *RTh, *RTl;
    const short *xh, *xl;
    const float *hF, *g0, *zb, *cF, *dtf;
    void* Out;
};

__global__ __launch_bounds__(1024, 1) void proj_row2_k(PArgs a) {
    __shared__ short tp[2 * TPP];
    const int tid = threadIdx.x, w = tid >> 6, ln = tid & 63;
    const int quad = ln >> 4, lr = ln & 15;
    const int m0 = blockIdx.x * 16;
    const int n0 = w * 32 + lr;

    float hreg[2], g0r[2], zbr[2];
    #pragma unroll
    for (int ct = 0; ct < 2; ++ct) {
        int n = n0 + ct * 16;
        hreg[ct] = a.hF[n];
        g0r[ct]  = a.g0[n];
        zbr[ct]  = a.zb[n];
    }
    float dtfv = a.dtf[0];

    // load x0 = c planes into LDS (1024 threads -> one vec per plane each)
    {
        int row = tid >> 6, oct = tid & 63;
        *(short8*)&tp[row * TPS + oct * 8] =
            *(const short8*)(a.xh + (size_t)(m0 + row) * 512 + oct * 8);
        *(short8*)&tp[TPP + row * TPS + oct * 8] =
            *(const short8*)(a.xl + (size_t)(m0 + row) * 512 + oct * 8);
    }
    __syncthreads();

    float4v q0r[2], xWr[2], u4[2], acc[2];

    for (int p = 0; p < 4; ++p) {
        // combo sub1: q0 = x R^T + g0
        row_sweep_lds(a.Rh, a.Rl, tp, w, quad, lr, acc);
        #pragma unroll
        for (int ct = 0; ct < 2; ++ct)
            #pragma unroll
            for (int r = 0; r < 4; ++r) q0r[ct][r] = acc[ct][r] + g0r[ct];
        // combo sub2: xW = x W1
        row_sweep_lds(a.Wh, a.Wl, tp, w, quad, lr, acc);
        xWr[0] = acc[0]; xWr[1] = acc[1];
        // combo sub3: t0 = min(h, x G^T), u0 = 0 (overwrite x planes with t0)
        row_sweep_lds(a.Gh, a.Gl, tp, w, quad, lr, acc);
        __syncthreads();
        #pragma unroll
        for (int ct = 0; ct < 2; ++ct) {
            int n = n0 + ct * 16;
            #pragma unroll
            for (int r = 0; r < 4; ++r) {
                u4[ct][r] = 0.f;
                split_lds(fminf(hreg[ct], acc[ct][r]), tp, quad * 4 + r, n);
            }
        }
        __syncthreads();

        // 15 ADMM iterations, all in-block
        for (int it = 0; it < ADMM_IT; ++it) {
            row_sweep_lds(a.Qh, a.Ql, tp, w, quad, lr, acc);
            __syncthreads();
            #pragma unroll
            for (int ct = 0; ct < 2; ++ct) {
                int n = n0 + ct * 16;
                #pragma unroll
                for (int r = 0; r < 4; ++r) {
                    float gz = acc[ct][r] + q0r[ct][r];
                    float wv = hreg[ct] - gz - u4[ct][r];
                    u4[ct][r] = fmaxf(0.f, -wv);
                    split_lds(hreg[ct] - fabsf(wv), tp, quad * 4 + r, n);
                }
            }
            __syncthreads();
        }

        // final z = t R + xW + zb; PGD (write x' planes) or emit
        row_sweep_lds(a.RTh, a.RTl, tp, w, quad, lr, acc);
        if (p < 3) {
            __syncthreads();
            #pragma unroll
            for (int ct = 0; ct < 2; ++ct) {
                int n = n0 + ct * 16;
                #pragma unroll
                for (int r = 0; r < 4; ++r) {
                    int m = m0 + quad * 4 + r;
                    float z = acc[ct][r] + xWr[ct][r] + zbr[ct];
                    float xv = (1.0f - ALPHA) * z + ALPHA * a.cF[(size_t)m * 512 + n];
                    split_lds(xv, tp, quad * 4 + r, n);
                }
            }
            __syncthreads();
        } else {
            #pragma unroll
            for (int ct = 0; ct < 2; ++ct) {
                int n = n0 + ct * 16;
                #pragma unroll
                for (int r = 0; r < 4; ++r) {
                    int m = m0 + quad * 4 + r;
                    size_t idx = (size_t)m * 512 + n;
                    float z = acc[ct][r] + xWr[ct][r] + zbr[ct];
                    if (dtfv > 0.5f) ((__hip_bfloat16*)a.Out)[idx] = __float2bfloat16(z);
                    else             ((float*)a.Out)[idx] = z;
                }
            }
        }
    }
}

// ---------------- host launcher ----------------

extern "C" void kernel_launch(void* const* d_in, const int* in_sizes, int n_in,
                              void* d_out, int out_size, void* d_ws, size_t ws_size,
                              hipStream_t stream) {
    const void* c_raw = d_in[0];
    const void* G_raw = d_in[1];
    const void* h_raw = d_in[2];
    const void* A_raw = d_in[3];
    const void* b_raw = d_in[4];

    float* w = (float*)d_ws;
    size_t o = 0;
    auto alloc = [&](size_t n) { float* p = w + o; o += (n + 63) & ~(size_t)63; return p; };

    float* cF  = alloc(BB * NN);
    float* GF  = alloc(MI * NN);
    float* AF  = alloc(ME * NN);
    float* hF  = alloc(MI);
    float* bF  = alloc(ME);
    float* Mm  = alloc(NN * NN);
    float* Xf0 = alloc(NN * NN);
    float* Xf1 = alloc(NN * NN);
    float* Rf  = alloc(MI * NN);
    float* Y   = alloc(NN * ME);
    float* T1  = alloc(NN * ME);
    float* Sm  = alloc(ME * ME);
    float* Si  = alloc(ME * ME);
    float* zb  = alloc(NN);
    float* g0  = alloc(MI);
    float* rs  = alloc(NN);
    float* dtf = alloc(16);

    short* sbp = (short*)(w + o);
    size_t so = 0;
    auto allocS = [&](size_t n) { short* p = sbp + so; so += (n + 127) & ~(size_t)127; return p; };

    short* GFh = allocS(MI * NN);  short* GFl = allocS(MI * NN);
    short* GTh = allocS(NN * MI);  short* GTl = allocS(NN * MI);
    short* Mmh = allocS(NN * NN);  short* Mml = allocS(NN * NN);
    short* X0h = allocS(NN * NN);  short* X0l = allocS(NN * NN);
    short* X1h = allocS(NN * NN);  short* X1l = allocS(NN * NN);
    short* W1h = allocS(NN * NN);  short* W1l = allocS(NN * NN);
    short* Rh  = allocS(MI * NN);  short* Rl  = allocS(MI * NN);
    short* RTh = allocS(NN * MI);  short* RTl = allocS(NN * MI);
    short* Qh  = allocS(MI * MI);  short* Ql  = allocS(MI * MI);
    short* xh  = allocS(BB * NN);  short* xl  = allocS(BB * NN);

    dim3 blk(256);
    auto cdiv = [](int a, int b) { return (a + b - 1) / b; };
    dim3 gSq(8, 32);

    detect_dtype_k<<<1, 256, 0, stream>>>((const unsigned short*)G_raw, dtf);
    ingest_all_k<<<cdiv(BB * NN, 256), blk, 0, stream>>>(
        c_raw, G_raw, h_raw, A_raw, b_raw,
        cF, xh, xl, GF, GFh, GFl, hF, AF, bF, rs, dtf);
    transpose_split_k<<<dim3(16, 16), blk, 0, stream>>>(GF, GTh, GTl);

    // M = I + G^T G  (f32 + planes + row-abs-sum atomics)
    gemm16_k<<<gSq, blk, 0, stream>>>(GTh, GTl, GTh, GTl, Mm, Mmh, Mml, rs, 1);
    // X0 = c0 I
    initX_k<<<256, blk, 0, stream>>>(rs, Xf0, X0h, X0l);

    // Newton-Schulz: 8 fused double-GEMM launches (row-local via symmetry)
    float* Xf[2] = {Xf0, Xf1};
    short* Xh[2] = {X0h, X1h};
    short* Xl[2] = {X0l, X1l};
    int cur = 0;
    for (int it = 0; it < NS_ITERS; ++it) {
        int nxt = cur ^ 1;
        ns_pair2_k<<<32, 1024, 0, stream>>>(Xh[cur], Xl[cur], Xf[cur], Mmh, Mml,
                                            Xf[nxt], Xh[nxt], Xl[nxt]);
        cur = nxt;
    }
    float* Minv = Xf[cur];  // cur == 0 for even NS_ITERS

    // Schur pieces
    Y_k<<<NN, blk, 0, stream>>>(Minv, AF, Y);
    Sm_k<<<1, blk, 0, stream>>>(AF, Y, Sm);
    inv16_k<<<1, 64, 0, stream>>>(Sm, Si);
    T1zb_k<<<NN / 16, blk, 0, stream>>>(Y, Si, bF, T1, zb);
    W1_k<<<NN * NN / 256, blk, 0, stream>>>(Minv, T1, Y, W1h, W1l);

    // R = G W1 (f32 + planes), RT planes, Q = R G^T (planes), g0
    gemm16_k<<<gSq, blk, 0, stream>>>(GFh, GFl, W1h, W1l, Rf, Rh, Rl, nullptr, 0);
    transpose_split_k<<<dim3(16, 16), blk, 0, stream>>>(Rf, RTh, RTl);
    gemm16_k<<<gSq, blk, 0, stream>>>(Rh, Rl, GFh, GFl, nullptr, Qh, Ql, nullptr, 9);
    g0_k<<<NN / 4, blk, 0, stream>>>(GF, zb, g0);

    // the whole 4-projection PGD pipeline: one launch, zero grid syncs
    PArgs pa;
    pa.Gh = GFh; pa.Gl = GFl; pa.Rh = Rh; pa.Rl = Rl; pa.Wh = W1h; pa.Wl = W1l;
    pa.Qh = Qh; pa.Ql = Ql; pa.RTh = RTh; pa.RTl = RTl;
    pa.xh = xh; pa.xl = xl;
    pa.hF = hF; pa.g0 = g0; pa.zb = zb; pa.cF = cF; pa.dtf = dtf;
    pa.Out = d_out;
    proj_row2_k<<<64, 1024, 0, stream>>>(pa);
}

// Round 11
// 688.300 us; speedup vs baseline: 4.4804x; 4.1851x over previous
//
#include <hip/hip_runtime.h>
#include <hip/hip_bf16.h>

// Problem constants (fixed by the reference)
#define BB 1024
#define NN 512
#define MI 512
#define ME 16
#define ALPHA 0.05f
#define NS_ITERS 8   // Gershgorin c0 -> r~0.9; 0.9^256 ~ 7e-12: converged
#define ADMM_IT 15

typedef __attribute__((ext_vector_type(8))) short short8;
typedef __attribute__((ext_vector_type(4))) float float4v;

__device__ inline short f2bf(float v) {
    __hip_bfloat16 b = __float2bfloat16(v);
    return *reinterpret_cast<short*>(&b);
}
__device__ inline float bf2f(short s) {
    __hip_bfloat16 b = *reinterpret_cast<__hip_bfloat16*>(&s);
    return __bfloat162float(b);
}
__device__ inline void split_store(float v, short* __restrict__ hi, short* __restrict__ lo, size_t idx) {
    short h = f2bf(v);
    hi[idx] = h;
    lo[idx] = f2bf(v - bf2f(h));
}

// ---------------- dtype auto-detect ----------------
__global__ void detect_dtype_k(const unsigned short* __restrict__ g_raw,
                               float* __restrict__ flag) {
    __shared__ int cnt;
    int tid = threadIdx.x;
    if (tid == 0) cnt = 0;
    __syncthreads();
    int local = 0;
    for (int i = tid; i < 8192; i += 256) {
        int e = (g_raw[i] >> 7) & 0xFF;
        if (e >= 0x83) local++;
    }
    atomicAdd(&cnt, local);
    __syncthreads();
    if (tid == 0) flag[0] = (cnt < 64) ? 1.0f : 0.0f;  // 1 => bf16 inputs
}

// ---------------- fused ingest: all 5 inputs + c/G splits ----------------
__global__ void ingest_all_k(const void* __restrict__ c_raw, const void* __restrict__ G_raw,
                             const void* __restrict__ h_raw, const void* __restrict__ A_raw,
                             const void* __restrict__ b_raw,
                             float* __restrict__ cF, short* __restrict__ xh, short* __restrict__ xl,
                             float* __restrict__ GF, short* __restrict__ GFh, short* __restrict__ GFl,
                             float* __restrict__ hF, float* __restrict__ AF, float* __restrict__ bF,
                             const float* __restrict__ flag) {
    int i = blockIdx.x * 256 + threadIdx.x;
    bool isbf = flag[0] > 0.5f;
    #define RD(p, idx) (isbf ? __bfloat162float(((const __hip_bfloat16*)(p))[idx]) : ((const float*)(p))[idx])
    if (i < BB * NN) { float v = RD(c_raw, i); cF[i] = v; split_store(v, xh, xl, i); }
    if (i < MI * NN) { float v = RD(G_raw, i); GF[i] = v; split_store(v, GFh, GFl, i); }
    if (i < MI)      hF[i] = RD(h_raw, i);
    if (i < ME * NN) AF[i] = RD(A_raw, i);
    if (i < ME)      bF[i] = RD(b_raw, i);
    #undef RD
}

// transpose 512x512 f32 -> bf16 hi/lo planes
__global__ void transpose_split_k(const float* __restrict__ src,
                                  short* __restrict__ dh, short* __restrict__ dl) {
    __shared__ float t[32][33];
    int bx = blockIdx.x * 32, by = blockIdx.y * 32;
    int tx = threadIdx.x & 31, ty0 = threadIdx.x >> 5;
    for (int i = ty0; i < 32; i += 8) t[i][tx] = src[(by + i) * 512 + bx + tx];
    __syncthreads();
    for (int i = ty0; i < 32; i += 8)
        split_store(t[tx][i], dh, dl, (size_t)(bx + i) * 512 + by + tx);
}

__global__ void row_abs_sum_k(const float* __restrict__ Mm, float* __restrict__ rs) {
    int row = blockIdx.x, lane = threadIdx.x;
    float s = 0.f;
    for (int j = lane; j < NN; j += 64) s += fabsf(Mm[row * NN + j]);
    for (int off = 32; off; off >>= 1) s += __shfl_down(s, off);
    if (lane == 0) rs[row] = s;
}

__global__ void max_c0_k(const float* __restrict__ rs, float* __restrict__ c0s) {
    int lane = threadIdx.x;
    float m = 0.f;
    for (int i = lane; i < NN; i += 64) m = fmaxf(m, rs[i]);
    for (int off = 32; off; off >>= 1) m = fmaxf(m, __shfl_down(m, off));
    if (lane == 0) c0s[0] = 2.0f / (1.0f + m);
}

__global__ void init_X_k(float* __restrict__ X, short* __restrict__ Xhi,
                         short* __restrict__ Xlo, const float* __restrict__ c0s) {
    int idx = blockIdx.x * 256 + threadIdx.x;
    if (idx < NN * NN) {
        int i = idx / NN, j = idx - i * NN;
        float v = (i == j) ? c0s[0] : 0.f;
        X[idx] = v;
        split_store(v, Xhi, Xlo, idx);
    }
}

__global__ void inv16_k(const float* __restrict__ S, float* __restrict__ Si) {
    int r = threadIdx.x;
    float a[16], bI[16];
    #pragma unroll
    for (int j = 0; j < 16; ++j) {
        a[j]  = (r < 16) ? S[r * 16 + j] : 0.f;
        bI[j] = (r < 16 && j == r) ? 1.f : 0.f;
    }
    for (int k = 0; k < 16; ++k) {
        float pa[16], pb[16];
        #pragma unroll
        for (int j = 0; j < 16; ++j) { pa[j] = __shfl(a[j], k); pb[j] = __shfl(bI[j], k); }
        float inv = 1.0f / pa[k];
        if (r == k) {
            #pragma unroll
            for (int j = 0; j < 16; ++j) { a[j] = pa[j] * inv; bI[j] = pb[j] * inv; }
        } else {
            float f = a[k] * inv;
            #pragma unroll
            for (int j = 0; j < 16; ++j) {
                a[j]  = fmaf(-f, pa[j], a[j]);
                bI[j] = fmaf(-f, pb[j], bI[j]);
            }
        }
    }
    if (r < 16)
        #pragma unroll
        for (int j = 0; j < 16; ++j) Si[r * 16 + j] = bI[j];
}

// ---------------- skinny ME-dim kernels ----------------
__global__ void Y_k(const float* __restrict__ Minv, const float* __restrict__ AF,
                    float* __restrict__ Y) {
    int m = blockIdx.x;
    int wv = threadIdx.x >> 6, lane = threadIdx.x & 63;
    float mv[8];
    #pragma unroll
    for (int i = 0; i < 8; ++i) mv[i] = Minv[m * 512 + lane + i * 64];
    #pragma unroll
    for (int jj = 0; jj < 4; ++jj) {
        int j = wv * 4 + jj;
        float s = 0.f;
        #pragma unroll
        for (int i = 0; i < 8; ++i) s += mv[i] * AF[j * 512 + lane + i * 64];
        for (int off = 32; off; off >>= 1) s += __shfl_down(s, off);
        if (lane == 0) Y[m * 16 + j] = s;
    }
}

__global__ void Sm_k(const float* __restrict__ AF, const float* __restrict__ Y,
                     float* __restrict__ Sm) {
    int i = threadIdx.x >> 4, j = threadIdx.x & 15;
    float s = 0.f;
    #pragma unroll 8
    for (int k = 0; k < 512; ++k) s += AF[i * 512 + k] * Y[k * 16 + j];
    Sm[i * 16 + j] = s;
}

__global__ void T1zb_k(const float* __restrict__ Y, const float* __restrict__ Si,
                       const float* __restrict__ bF, float* __restrict__ T1,
                       float* __restrict__ zb) {
    int m = blockIdx.x * 16 + (threadIdx.x >> 4), j = threadIdx.x & 15;
    float s = 0.f;
    #pragma unroll
    for (int k = 0; k < 16; ++k) s += Y[m * 16 + k] * Si[k * 16 + j];
    T1[m * 16 + j] = s;
    float v = s * bF[j];
    v += __shfl_down(v, 8); v += __shfl_down(v, 4);
    v += __shfl_down(v, 2); v += __shfl_down(v, 1);
    if (j == 0) zb[m] = v;
}

// W1 = Minv - T1 Y^T -> planes only (into Bcat W1 slice)
__global__ void W1_k(const float* __restrict__ Minv, const float* __restrict__ T1,
                     const float* __restrict__ Y,
                     short* __restrict__ W1h, short* __restrict__ W1l) {
    int idx = blockIdx.x * 256 + threadIdx.x;
    int m = idx >> 9, n = idx & 511;
    float s = Minv[idx];
    #pragma unroll
    for (int k = 0; k < 16; ++k) s -= T1[m * 16 + k] * Y[n * 16 + k];
    split_store(s, W1h, W1l, idx);
}

__global__ void g0_k(const float* __restrict__ GF, const float* __restrict__ zb,
                     float* __restrict__ g0) {
    int m = blockIdx.x * 4 + (threadIdx.x >> 6);
    int lane = threadIdx.x & 63;
    float s = 0.f;
    #pragma unroll
    for (int i = 0; i < 8; ++i) s += GF[m * 512 + lane + i * 64] * zb[lane + i * 64];
    for (int off = 32; off; off >>= 1) s += __shfl_down(s, off);
    if (lane == 0) g0[m] = s;
}

// ---------------- pipelined split-bf16 MFMA NT GEMM, K = 512 ----------------
// Tile 16 rows x 64 cols, 4 waves (wave w -> 16-col tile w). k-chunk 128,
// register prefetch of next chunk. Two acc chains (hh | hl+lh).
// epi: 0 C=acc (+planes if Chi)    1 C=acc+(m==n), planes   2 C=2E-acc, planes
//      6 z=acc+E+v1[n]; x'=(1-a)z+a*Xtra; planes            (final z + PGD)
//      7 combo by col-segment: [G | R | W1] -> t0-hi+U=0 | q0=acc+E[n'] | Xtra=acc
//      8 z=acc+E+v1[n]; emit to Out (bf16/f32 per dtf)
//      9 planes only
#define CH 128
#define LDC 136

__global__ __launch_bounds__(256) void mfma_gemm2(
    const short* __restrict__ Ahi, const short* __restrict__ Alo,
    const short* __restrict__ Bhi, const short* __restrict__ Blo,
    float* __restrict__ C, short* __restrict__ Chi, short* __restrict__ Clo,
    const float* __restrict__ E, const float* __restrict__ v1,
    float* __restrict__ U, float* __restrict__ Xtra,
    const float* __restrict__ dtf, void* __restrict__ Out, int epi)
{
    __shared__ short Ash[2][16 * LDC];
    __shared__ short Bsh[2][64 * LDC];
    const int tid = threadIdx.x;
    const int wv = tid >> 6, ln = tid & 63;
    const int quad = ln >> 4, lr = ln & 15;
    const int m0 = blockIdx.y * 16, n0 = blockIdx.x * 64;

    float4v acc1 = {0.f, 0.f, 0.f, 0.f};
    float4v acc2 = {0.f, 0.f, 0.f, 0.f};

    short8 pa[2], pb[8];
    #pragma unroll
    for (int i = 0; i < 2; ++i) {
        int s = tid + 256 * i; int pl = s >> 8, rem = s & 255, row = rem >> 4, oct = rem & 15;
        const short* P = pl ? Alo : Ahi;
        pa[i] = *(const short8*)(P + (size_t)(m0 + row) * 512 + oct * 8);
    }
    #pragma unroll
    for (int i = 0; i < 8; ++i) {
        int s = tid + 256 * i; int pl = s >> 10, rem = s & 1023, row = rem >> 4, oct = rem & 15;
        const short* P = pl ? Blo : Bhi;
        pb[i] = *(const short8*)(P + (size_t)(n0 + row) * 512 + oct * 8);
    }

    for (int c = 0; c < 4; ++c) {
        if (c) __syncthreads();
        #pragma unroll
        for (int i = 0; i < 2; ++i) {
            int s = tid + 256 * i; int pl = s >> 8, rem = s & 255, row = rem >> 4, oct = rem & 15;
            *(short8*)&Ash[pl][row * LDC + oct * 8] = pa[i];
        }
        #pragma unroll
        for (int i = 0; i < 8; ++i) {
            int s = tid + 256 * i; int pl = s >> 10, rem = s & 1023, row = rem >> 4, oct = rem & 15;
            *(short8*)&Bsh[pl][row * LDC + oct * 8] = pb[i];
        }
        __syncthreads();
        if (c + 1 < 4) {
            int kb = (c + 1) * CH;
            #pragma unroll
            for (int i = 0; i < 2; ++i) {
                int s = tid + 256 * i; int pl = s >> 8, rem = s & 255, row = rem >> 4, oct = rem & 15;
                const short* P = pl ? Alo : Ahi;
                pa[i] = *(const short8*)(P + (size_t)(m0 + row) * 512 + kb + oct * 8);
            }
            #pragma unroll
            for (int i = 0; i < 8; ++i) {
                int s = tid + 256 * i; int pl = s >> 10, rem = s & 1023, row = rem >> 4, oct = rem & 15;
                const short* P = pl ? Blo : Bhi;
                pb[i] = *(const short8*)(P + (size_t)(n0 + row) * 512 + kb + oct * 8);
            }
        }
        #pragma unroll
        for (int ks = 0; ks < 4; ++ks) {
            int ko = (ks * 4 + quad) * 8;
            short8 ah = *(const short8*)&Ash[0][lr * LDC + ko];
            short8 al = *(const short8*)&Ash[1][lr * LDC + ko];
            short8 bh = *(const short8*)&Bsh[0][(wv * 16 + lr) * LDC + ko];
            short8 bl = *(const short8*)&Bsh[1][(wv * 16 + lr) * LDC + ko];
            acc1 = __builtin_amdgcn_mfma_f32_16x16x32_bf16(ah, bh, acc1, 0, 0, 0);
            acc2 = __builtin_amdgcn_mfma_f32_16x16x32_bf16(ah, bl, acc2, 0, 0, 0);
            acc2 = __builtin_amdgcn_mfma_f32_16x16x32_bf16(al, bh, acc2, 0, 0, 0);
        }
    }

    // C/D layout: col = lane&15, row = quad*4 + reg
    #pragma unroll
    for (int r = 0; r < 4; ++r) {
        int m = m0 + quad * 4 + r;
        int n = n0 + wv * 16 + lr;
        float a = acc1[r] + acc2[r];
        if (epi == 7) {
            int seg = n0 >> 9;
            int nl = n - (seg << 9);
            size_t idx = (size_t)m * 512 + nl;
            if (seg == 0) {
                float t0 = fminf(v1[nl], a);
                U[idx] = 0.f;
                Chi[idx] = f2bf(t0);     // bf16-only t for the ADMM chain
            } else if (seg == 1) {
                C[idx] = a + E[nl];
            } else {
                Xtra[idx] = a;
            }
            continue;
        }
        size_t idx = (size_t)m * 512 + n;
        if (epi == 0) {
            C[idx] = a;
            if (Chi) split_store(a, Chi, Clo, idx);
        } else if (epi == 1) {
            a += (m == n) ? 1.f : 0.f;
            C[idx] = a;
            split_store(a, Chi, Clo, idx);
        } else if (epi == 2) {
            a = 2.f * E[idx] - a;
            C[idx] = a;
            split_store(a, Chi, Clo, idx);
        } else if (epi == 6) {
            float z = a + E[idx] + v1[n];
            float xp = (1.0f - ALPHA) * z + ALPHA * Xtra[idx];
            split_store(xp, Chi, Clo, idx);
        } else if (epi == 8) {
            float z = a + E[idx] + v1[n];
            if (dtf[0] > 0.5f) ((__hip_bfloat16*)Out)[idx] = __float2bfloat16(z);
            else               ((float*)Out)[idx] = z;
        } else {  // 9: planes only
            split_store(a, Chi, Clo, idx);
        }
    }
}

// ---------------- bf16-single-plane ADMM step GEMM ----------------
// t' = h - |h - (t Q + q0) - u|; u' = relu(-(h - Gz - u)). t and Q bf16-only
// (q0/u/h stay f32: q0 dominates Gz so precision is preserved; fixed-point
// shift from bf16 tQ ~1e-2 << 0.068 threshold margin). Staging bytes and MFMA
// count drop vs the hi/lo kernel (1 MFMA per k-step instead of 3).
// dl != nullptr on the last iteration: also emit the t-lo plane so the final
// z = tR GEMM runs at full hi/lo precision.
__global__ __launch_bounds__(256) void admm_bf16_k(
    const short* __restrict__ Ab, const short* __restrict__ Bb,
    const float* __restrict__ q0, const float* __restrict__ hF,
    float* __restrict__ uB, short* __restrict__ dh, short* __restrict__ dl)
{
    __shared__ short As[16 * LDC];
    __shared__ short Bs[64 * LDC];
    const int tid = threadIdx.x;
    const int wv = tid >> 6, ln = tid & 63;
    const int quad = ln >> 4, lr = ln & 15;
    const int m0 = blockIdx.y * 16, n0 = blockIdx.x * 64;

    float4v acc1 = {0.f, 0.f, 0.f, 0.f};
    float4v acc2 = {0.f, 0.f, 0.f, 0.f};

    short8 pa, pb[4];
    {
        int row = tid >> 4, oct = tid & 15;
        pa = *(const short8*)(Ab + (size_t)(m0 + row) * 512 + oct * 8);
    }
    #pragma unroll
    for (int i = 0; i < 4; ++i) {
        int s = tid + 256 * i; int row = s >> 4, oct = s & 15;
        pb[i] = *(const short8*)(Bb + (size_t)(n0 + row) * 512 + oct * 8);
    }

    for (int c = 0; c < 4; ++c) {
        if (c) __syncthreads();
        {
            int row = tid >> 4, oct = tid & 15;
            *(short8*)&As[row * LDC + oct * 8] = pa;
        }
        #pragma unroll
        for (int i = 0; i < 4; ++i) {
            int s = tid + 256 * i; int row = s >> 4, oct = s & 15;
            *(short8*)&Bs[row * LDC + oct * 8] = pb[i];
        }
        __syncthreads();
        if (c + 1 < 4) {
            int kb = (c + 1) * CH;
            {
                int row = tid >> 4, oct = tid & 15;
                pa = *(const short8*)(Ab + (size_t)(m0 + row) * 512 + kb + oct * 8);
            }
            #pragma unroll
            for (int i = 0; i < 4; ++i) {
                int s = tid + 256 * i; int row = s >> 4, oct = s & 15;
                pb[i] = *(const short8*)(Bb + (size_t)(n0 + row) * 512 + kb + oct * 8);
            }
        }
        #pragma unroll
        for (int ks = 0; ks < 4; ++ks) {
            int ko = (ks * 4 + quad) * 8;
            short8 a = *(const short8*)&As[lr * LDC + ko];
            short8 b = *(const short8*)&Bs[(wv * 16 + lr) * LDC + ko];
            if (ks & 1) acc2 = __builtin_amdgcn_mfma_f32_16x16x32_bf16(a, b, acc2, 0, 0, 0);
            else        acc1 = __builtin_amdgcn_mfma_f32_16x16x32_bf16(a, b, acc1, 0, 0, 0);
        }
    }

    #pragma unroll
    for (int r = 0; r < 4; ++r) {
        int m = m0 + quad * 4 + r;
        int n = n0 + wv * 16 + lr;
        size_t idx = (size_t)m * 512 + n;
        float gz = acc1[r] + acc2[r] + q0[idx];
        float hn = hF[n];
        float w = hn - gz - uB[idx];
        uB[idx] = fmaxf(0.f, -w);
        float t2 = hn - fabsf(w);
        short hh = f2bf(t2);
        dh[idx] = hh;
        if (dl) dl[idx] = f2bf(t2 - bf2f(hh));
    }
}

// ---------------- host launcher ----------------

extern "C" void kernel_launch(void* const* d_in, const int* in_sizes, int n_in,
                              void* d_out, int out_size, void* d_ws, size_t ws_size,
                              hipStream_t stream) {
    const void* c_raw = d_in[0];
    const void* G_raw = d_in[1];
    const void* h_raw = d_in[2];
    const void* A_raw = d_in[3];
    const void* b_raw = d_in[4];

    float* w = (float*)d_ws;
    size_t o = 0;
    auto alloc = [&](size_t n) { float* p = w + o; o += (n + 63) & ~(size_t)63; return p; };

    float* cF  = alloc(BB * NN);
    float* GF  = alloc(MI * NN);
    float* AF  = alloc(ME * NN);
    float* hF  = alloc(MI);
    float* bF  = alloc(ME);
    float* Mm  = alloc(NN * NN);
    float* Xf0 = alloc(NN * NN);
    float* Xf1 = alloc(NN * NN);
    float* Rf  = alloc(MI * NN);
    float* Y   = alloc(NN * ME);
    float* T1  = alloc(NN * ME);
    float* Sm  = alloc(ME * ME);
    float* Si  = alloc(ME * ME);
    float* zb  = alloc(NN);
    float* g0  = alloc(MI);
    float* rs  = alloc(NN);
    float* c0s = alloc(16);
    float* dtf = alloc(16);
    float* q0  = alloc(BB * MI);
    float* xW  = alloc(BB * NN);
    float* uB  = alloc(BB * MI);

    short* sbp = (short*)(w + o);
    size_t so = 0;
    auto allocS = [&](size_t n) { short* p = sbp + so; so += (n + 127) & ~(size_t)127; return p; };

    // Bcat = [G(512) ; R(512) ; W1(512)] x 512, contiguous per plane
    short* Bcat_h = allocS(3 * 512 * 512);
    short* Bcat_l = allocS(3 * 512 * 512);
    short* GFh = Bcat_h;              short* GFl = Bcat_l;
    short* Rh  = Bcat_h + 512 * 512;  short* Rl  = Bcat_l + 512 * 512;
    short* W1h = Bcat_h + 1024 * 512; short* W1l = Bcat_l + 1024 * 512;

    short* GTh = allocS(NN * MI);  short* GTl = allocS(NN * MI);
    short* Mmh = allocS(NN * NN);  short* Mml = allocS(NN * NN);
    short* X0h = allocS(NN * NN);  short* X0l = allocS(NN * NN);
    short* X1h = allocS(NN * NN);  short* X1l = allocS(NN * NN);
    short* Uh  = allocS(NN * NN);  short* Ul  = allocS(NN * NN);
    short* RTh = allocS(NN * MI);  short* RTl = allocS(NN * MI);
    short* Qh  = allocS(MI * MI);  short* Ql  = allocS(MI * MI);
    short* xh  = allocS(BB * NN);  short* xl  = allocS(BB * NN);
    short* tAh = allocS(BB * MI);  short* tAl = allocS(BB * MI);
    short* tBh = allocS(BB * MI);  short* tBl = allocS(BB * MI);

    dim3 blk(256);
    auto cdiv = [](int a, int b) { return (a + b - 1) / b; };
    dim3 gSq(8, 32);    // 512x512 outputs
    dim3 gBt(8, 64);    // 1024x512 outputs (16-row tiles, 512 blocks = 2/CU)
    dim3 gCombo(24, 64);

    detect_dtype_k<<<1, 256, 0, stream>>>((const unsigned short*)G_raw, dtf);
    ingest_all_k<<<cdiv(BB * NN, 256), blk, 0, stream>>>(
        c_raw, G_raw, h_raw, A_raw, b_raw,
        cF, xh, xl, GF, GFh, GFl, hF, AF, bF, dtf);

    // G^T planes
    transpose_split_k<<<dim3(16, 16), blk, 0, stream>>>(GF, GTh, GTl);

    // M = I + G^T G
    mfma_gemm2<<<gSq, blk, 0, stream>>>(GTh, GTl, GTh, GTl, Mm, Mmh, Mml,
                                        nullptr, nullptr, nullptr, nullptr, nullptr, nullptr, 1);

    // Newton-Schulz inverse
    row_abs_sum_k<<<NN, 64, 0, stream>>>(Mm, rs);
    max_c0_k<<<1, 64, 0, stream>>>(rs, c0s);
    init_X_k<<<cdiv(NN * NN, 256), blk, 0, stream>>>(Xf0, X0h, X0l, c0s);
    float* Xf[2] = {Xf0, Xf1};
    short* Xh[2] = {X0h, X1h};
    short* Xl[2] = {X0l, X1l};
    int cur = 0;
    for (int it = 0; it < NS_ITERS; ++it) {
        int nxt = cur ^ 1;
        // U = X * M (planes only)
        mfma_gemm2<<<gSq, blk, 0, stream>>>(Xh[cur], Xl[cur], Mmh, Mml, nullptr, Uh, Ul,
                                            nullptr, nullptr, nullptr, nullptr, nullptr, nullptr, 9);
        // X' = 2X - U*X
        mfma_gemm2<<<gSq, blk, 0, stream>>>(Uh, Ul, Xh[cur], Xl[cur], Xf[nxt], Xh[nxt], Xl[nxt],
                                            Xf[cur], nullptr, nullptr, nullptr, nullptr, nullptr, 2);
        cur = nxt;
    }
    float* Minv = Xf[cur];

    // Schur pieces
    Y_k<<<NN, blk, 0, stream>>>(Minv, AF, Y);
    Sm_k<<<1, blk, 0, stream>>>(AF, Y, Sm);
    inv16_k<<<1, 64, 0, stream>>>(Sm, Si);
    T1zb_k<<<NN / 16, blk, 0, stream>>>(Y, Si, bF, T1, zb);
    W1_k<<<NN * NN / 256, blk, 0, stream>>>(Minv, T1, Y, W1h, W1l);

    // R = G W1 (f32 + planes into Bcat R slice)
    mfma_gemm2<<<gSq, blk, 0, stream>>>(GFh, GFl, W1h, W1l, Rf, Rh, Rl,
                                        nullptr, nullptr, nullptr, nullptr, nullptr, nullptr, 0);
    transpose_split_k<<<dim3(16, 16), blk, 0, stream>>>(Rf, RTh, RTl);
    // Q = R G^T (planes; ADMM uses hi only)
    mfma_gemm2<<<gSq, blk, 0, stream>>>(Rh, Rl, GFh, GFl, nullptr, Qh, Ql,
                                        nullptr, nullptr, nullptr, nullptr, nullptr, nullptr, 9);
    g0_k<<<NN / 4, blk, 0, stream>>>(GF, zb, g0);

    // 4 projections (x0 = c, planes already in xh/xl from ingest)
    for (int p = 0; p < 4; ++p) {
        // combo: [t0-init | q0 | xW] in one launch, B = [G;R;W1]
        mfma_gemm2<<<gCombo, blk, 0, stream>>>(xh, xl, Bcat_h, Bcat_l, q0, tAh, tAl,
                                               g0, hF, uB, xW, nullptr, nullptr, 7);
        for (int it = 0; it < ADMM_IT; ++it) {
            const short* sh = (it & 1) ? tBh : tAh;
            short* dh = (it & 1) ? tAh : tBh;
            short* dl = (it == ADMM_IT - 1) ? tBl : nullptr;  // last iter -> lo plane too
            admm_bf16_k<<<gBt, blk, 0, stream>>>(sh, Qh, q0, hF, uB, dh, dl);
        }
        // final z = t R + xW + zb (t in tB hi/lo after 15 iters); PGD split or emit
        if (p < 3) {
            mfma_gemm2<<<gBt, blk, 0, stream>>>(tBh, tBl, RTh, RTl, nullptr, xh, xl,
                                                xW, zb, nullptr, cF, nullptr, nullptr, 6);
        } else {
            mfma_gemm2<<<gBt, blk, 0, stream>>>(tBh, tBl, RTh, RTl, nullptr, nullptr, nullptr,
                                                xW, zb, nullptr, nullptr, dtf, d_out, 8);
        }
    }
}

// Round 12
// 629.699 us; speedup vs baseline: 4.8973x; 1.0931x over previous
//
#include <hip/hip_runtime.h>
#include <hip/hip_bf16.h>

// Problem constants (fixed by the reference)
#define BB 1024
#define NN 512
#define MI 512
#define ME 16
#define ALPHA 0.05f
#define ADMM_IT 15
#define NS_CHEAP 5   // X1 direct + 5 single-plane pairs + 1 hi/lo pair = 7 NS iters
                     // E1=0.81 -> E6~max(0.81^32, bf16-Mtilde floor ~1e-2); final pair: E7~1e-4

typedef __attribute__((ext_vector_type(8))) short short8;
typedef __attribute__((ext_vector_type(4))) float float4v;

__device__ inline short f2bf(float v) {
    __hip_bfloat16 b = __float2bfloat16(v);
    return *reinterpret_cast<short*>(&b);
}
__device__ inline float bf2f(short s) {
    __hip_bfloat16 b = *reinterpret_cast<__hip_bfloat16*>(&s);
    return __bfloat162float(b);
}
__device__ inline void split_store(float v, short* __restrict__ hi, short* __restrict__ lo, size_t idx) {
    short h = f2bf(v);
    hi[idx] = h;
    lo[idx] = f2bf(v - bf2f(h));
}

// ---------------- dtype auto-detect ----------------
__global__ void detect_dtype_k(const unsigned short* __restrict__ g_raw,
                               float* __restrict__ flag) {
    __shared__ int cnt;
    int tid = threadIdx.x;
    if (tid == 0) cnt = 0;
    __syncthreads();
    int local = 0;
    for (int i = tid; i < 8192; i += 256) {
        int e = (g_raw[i] >> 7) & 0xFF;
        if (e >= 0x83) local++;
    }
    atomicAdd(&cnt, local);
    __syncthreads();
    if (tid == 0) flag[0] = (cnt < 64) ? 1.0f : 0.0f;  // 1 => bf16 inputs
}

// ---------------- fused ingest (also zeroes rs) ----------------
__global__ void ingest_all_k(const void* __restrict__ c_raw, const void* __restrict__ G_raw,
                             const void* __restrict__ h_raw, const void* __restrict__ A_raw,
                             const void* __restrict__ b_raw,
                             float* __restrict__ cF, short* __restrict__ xh, short* __restrict__ xl,
                             float* __restrict__ GF, short* __restrict__ GFh, short* __restrict__ GFl,
                             float* __restrict__ hF, float* __restrict__ AF, float* __restrict__ bF,
                             float* __restrict__ rs, const float* __restrict__ flag) {
    int i = blockIdx.x * 256 + threadIdx.x;
    bool isbf = flag[0] > 0.5f;
    #define RD(p, idx) (isbf ? __bfloat162float(((const __hip_bfloat16*)(p))[idx]) : ((const float*)(p))[idx])
    if (i < BB * NN) { float v = RD(c_raw, i); cF[i] = v; split_store(v, xh, xl, i); }
    if (i < MI * NN) { float v = RD(G_raw, i); GF[i] = v; split_store(v, GFh, GFl, i); }
    if (i < MI)      hF[i] = RD(h_raw, i);
    if (i < ME * NN) AF[i] = RD(A_raw, i);
    if (i < ME)      bF[i] = RD(b_raw, i);
    if (i < NN)      rs[i] = 0.f;
    #undef RD
}

// transpose 512x512 f32 -> bf16 hi/lo planes
__global__ void transpose_split_k(const float* __restrict__ src,
                                  short* __restrict__ dh, short* __restrict__ dl) {
    __shared__ float t[32][33];
    int bx = blockIdx.x * 32, by = blockIdx.y * 32;
    int tx = threadIdx.x & 31, ty0 = threadIdx.x >> 5;
    for (int i = ty0; i < 32; i += 8) t[i][tx] = src[(by + i) * 512 + bx + tx];
    __syncthreads();
    for (int i = ty0; i < 32; i += 8)
        split_store(t[tx][i], dh, dl, (size_t)(bx + i) * 512 + by + tx);
}

// X1 = 2c0*I - c0^2*M  (bf16-hi only; NS self-corrects), c0 from Gershgorin rs
__global__ void initX1_k(const float* __restrict__ rs, const float* __restrict__ Mm,
                         short* __restrict__ X1h) {
    int ln = threadIdx.x & 63;
    float mx = 0.f;
    #pragma unroll
    for (int i = 0; i < 8; ++i) mx = fmaxf(mx, rs[ln + i * 64]);
    for (int off = 32; off; off >>= 1) mx = fmaxf(mx, __shfl_down(mx, off));
    float c0 = 2.0f / (1.0f + __shfl(mx, 0));
    #pragma unroll
    for (int j = 0; j < 4; ++j) {
        int idx = blockIdx.x * 1024 + j * 256 + threadIdx.x;
        int r = idx >> 9, cc = idx & 511;
        float v = -c0 * c0 * Mm[idx] + ((r == cc) ? 2.0f * c0 : 0.f);
        X1h[idx] = f2bf(v);
    }
}

// fused Sm = A Y (16x16) then Si = inv(Sm), one block
__global__ void sm_inv_k(const float* __restrict__ AF, const float* __restrict__ Y,
                         float* __restrict__ Si) {
    __shared__ float Sm[256];
    int i = threadIdx.x >> 4, j = threadIdx.x & 15;
    float s = 0.f;
    #pragma unroll 8
    for (int k = 0; k < 512; ++k) s += AF[i * 512 + k] * Y[k * 16 + j];
    Sm[i * 16 + j] = s;
    __syncthreads();
    if (threadIdx.x < 64) {
        int r = threadIdx.x;
        float a[16], bI[16];
        #pragma unroll
        for (int jj = 0; jj < 16; ++jj) {
            a[jj]  = (r < 16) ? Sm[r * 16 + jj] : 0.f;
            bI[jj] = (r < 16 && jj == r) ? 1.f : 0.f;
        }
        for (int k = 0; k < 16; ++k) {
            float pa[16], pb[16];
            #pragma unroll
            for (int jj = 0; jj < 16; ++jj) { pa[jj] = __shfl(a[jj], k); pb[jj] = __shfl(bI[jj], k); }
            float inv = 1.0f / pa[k];
            if (r == k) {
                #pragma unroll
                for (int jj = 0; jj < 16; ++jj) { a[jj] = pa[jj] * inv; bI[jj] = pb[jj] * inv; }
            } else {
                float f = a[k] * inv;
                #pragma unroll
                for (int jj = 0; jj < 16; ++jj) {
                    a[jj]  = fmaf(-f, pa[jj], a[jj]);
                    bI[jj] = fmaf(-f, pb[jj], bI[jj]);
                }
            }
        }
        if (r < 16)
            #pragma unroll
            for (int jj = 0; jj < 16; ++jj) Si[r * 16 + jj] = bI[jj];
    }
}

// ---------------- skinny ME-dim kernels ----------------
__global__ void Y_k(const float* __restrict__ Minv, const float* __restrict__ AF,
                    float* __restrict__ Y) {
    int m = blockIdx.x;
    int wv = threadIdx.x >> 6, lane = threadIdx.x & 63;
    float mv[8];
    #pragma unroll
    for (int i = 0; i < 8; ++i) mv[i] = Minv[m * 512 + lane + i * 64];
    #pragma unroll
    for (int jj = 0; jj < 4; ++jj) {
        int j = wv * 4 + jj;
        float s = 0.f;
        #pragma unroll
        for (int i = 0; i < 8; ++i) s += mv[i] * AF[j * 512 + lane + i * 64];
        for (int off = 32; off; off >>= 1) s += __shfl_down(s, off);
        if (lane == 0) Y[m * 16 + j] = s;
    }
}

__global__ void T1zb_k(const float* __restrict__ Y, const float* __restrict__ Si,
                       const float* __restrict__ bF, float* __restrict__ T1,
                       float* __restrict__ zb) {
    int m = blockIdx.x * 16 + (threadIdx.x >> 4), j = threadIdx.x & 15;
    float s = 0.f;
    #pragma unroll
    for (int k = 0; k < 16; ++k) s += Y[m * 16 + k] * Si[k * 16 + j];
    T1[m * 16 + j] = s;
    float v = s * bF[j];
    v += __shfl_down(v, 8); v += __shfl_down(v, 4);
    v += __shfl_down(v, 2); v += __shfl_down(v, 1);
    if (j == 0) zb[m] = v;
}

// W1 = Minv - T1 Y^T -> planes only (into Bcat W1 slice)
__global__ void W1_k(const float* __restrict__ Minv, const float* __restrict__ T1,
                     const float* __restrict__ Y,
                     short* __restrict__ W1h, short* __restrict__ W1l) {
    int idx = blockIdx.x * 256 + threadIdx.x;
    int m = idx >> 9, n = idx & 511;
    float s = Minv[idx];
    #pragma unroll
    for (int k = 0; k < 16; ++k) s -= T1[m * 16 + k] * Y[n * 16 + k];
    split_store(s, W1h, W1l, idx);
}

__global__ void g0_k(const float* __restrict__ GF, const float* __restrict__ zb,
                     float* __restrict__ g0) {
    int m = blockIdx.x * 4 + (threadIdx.x >> 6);
    int lane = threadIdx.x & 63;
    float s = 0.f;
    #pragma unroll
    for (int i = 0; i < 8; ++i) s += GF[m * 512 + lane + i * 64] * zb[lane + i * 64];
    for (int off = 32; off; off >>= 1) s += __shfl_down(s, off);
    if (lane == 0) g0[m] = s;
}

// ---------------- pipelined split-bf16 MFMA NT GEMM, K = 512 ----------------
// Tile 16 rows x 64 cols, 4 waves. k-chunk 128, register prefetch of next chunk.
// epi: 0 C=acc (+planes if Chi)    1 C=acc+(m==n), planes, rs row-abs atomics (M build)
//      2 C=2E-acc, planes (NS final X-step)
//      6 z=acc+E+v1[n]; x'=(1-a)z+a*Xtra; planes            (final z + PGD)
//      7 combo by col-segment: [G | R | W1] -> t0-hi+U=0 | q0=acc+E[n'] | Xtra=acc
//      8 z=acc+E+v1[n]; emit to Out (bf16/f32 per dtf)
//      9 planes only
#define CH 128
#define LDC 136

__global__ __launch_bounds__(256) void mfma_gemm2(
    const short* __restrict__ Ahi, const short* __restrict__ Alo,
    const short* __restrict__ Bhi, const short* __restrict__ Blo,
    float* __restrict__ C, short* __restrict__ Chi, short* __restrict__ Clo,
    const float* __restrict__ E, const float* __restrict__ v1,
    float* __restrict__ U, float* __restrict__ Xtra,
    const float* __restrict__ dtf, void* __restrict__ Out, int epi)
{
    __shared__ short Ash[2][16 * LDC];
    __shared__ short Bsh[2][64 * LDC];
    const int tid = threadIdx.x;
    const int wv = tid >> 6, ln = tid & 63;
    const int quad = ln >> 4, lr = ln & 15;
    const int m0 = blockIdx.y * 16, n0 = blockIdx.x * 64;

    float4v acc1 = {0.f, 0.f, 0.f, 0.f};
    float4v acc2 = {0.f, 0.f, 0.f, 0.f};

    short8 pa[2], pb[8];
    #pragma unroll
    for (int i = 0; i < 2; ++i) {
        int s = tid + 256 * i; int pl = s >> 8, rem = s & 255, row = rem >> 4, oct = rem & 15;
        const short* P = pl ? Alo : Ahi;
        pa[i] = *(const short8*)(P + (size_t)(m0 + row) * 512 + oct * 8);
    }
    #pragma unroll
    for (int i = 0; i < 8; ++i) {
        int s = tid + 256 * i; int pl = s >> 10, rem = s & 1023, row = rem >> 4, oct = rem & 15;
        const short* P = pl ? Blo : Bhi;
        pb[i] = *(const short8*)(P + (size_t)(n0 + row) * 512 + oct * 8);
    }

    for (int c = 0; c < 4; ++c) {
        if (c) __syncthreads();
        #pragma unroll
        for (int i = 0; i < 2; ++i) {
            int s = tid + 256 * i; int pl = s >> 8, rem = s & 255, row = rem >> 4, oct = rem & 15;
            *(short8*)&Ash[pl][row * LDC + oct * 8] = pa[i];
        }
        #pragma unroll
        for (int i = 0; i < 8; ++i) {
            int s = tid + 256 * i; int pl = s >> 10, rem = s & 1023, row = rem >> 4, oct = rem & 15;
            *(short8*)&Bsh[pl][row * LDC + oct * 8] = pb[i];
        }
        __syncthreads();
        if (c + 1 < 4) {
            int kb = (c + 1) * CH;
            #pragma unroll
            for (int i = 0; i < 2; ++i) {
                int s = tid + 256 * i; int pl = s >> 8, rem = s & 255, row = rem >> 4, oct = rem & 15;
                const short* P = pl ? Alo : Ahi;
                pa[i] = *(const short8*)(P + (size_t)(m0 + row) * 512 + kb + oct * 8);
            }
            #pragma unroll
            for (int i = 0; i < 8; ++i) {
                int s = tid + 256 * i; int pl = s >> 10, rem = s & 1023, row = rem >> 4, oct = rem & 15;
                const short* P = pl ? Blo : Bhi;
                pb[i] = *(const short8*)(P + (size_t)(n0 + row) * 512 + kb + oct * 8);
            }
        }
        #pragma unroll
        for (int ks = 0; ks < 4; ++ks) {
            int ko = (ks * 4 + quad) * 8;
            short8 ah = *(const short8*)&Ash[0][lr * LDC + ko];
            short8 al = *(const short8*)&Ash[1][lr * LDC + ko];
            short8 bh = *(const short8*)&Bsh[0][(wv * 16 + lr) * LDC + ko];
            short8 bl = *(const short8*)&Bsh[1][(wv * 16 + lr) * LDC + ko];
            acc1 = __builtin_amdgcn_mfma_f32_16x16x32_bf16(ah, bh, acc1, 0, 0, 0);
            acc2 = __builtin_amdgcn_mfma_f32_16x16x32_bf16(ah, bl, acc2, 0, 0, 0);
            acc2 = __builtin_amdgcn_mfma_f32_16x16x32_bf16(al, bh, acc2, 0, 0, 0);
        }
    }

    // C/D layout: col = lane&15, row = quad*4 + reg
    #pragma unroll
    for (int r = 0; r < 4; ++r) {
        int m = m0 + quad * 4 + r;
        int n = n0 + wv * 16 + lr;
        float a = acc1[r] + acc2[r];
        if (epi == 7) {
            int seg = n0 >> 9;
            int nl = n - (seg << 9);
            size_t idx = (size_t)m * 512 + nl;
            if (seg == 0) {
                float t0 = fminf(v1[nl], a);
                U[idx] = 0.f;
                Chi[idx] = f2bf(t0);     // bf16-only t for the ADMM chain
            } else if (seg == 1) {
                C[idx] = a + E[nl];
            } else {
                Xtra[idx] = a;
            }
            continue;
        }
        size_t idx = (size_t)m * 512 + n;
        if (epi == 0) {
            C[idx] = a;
            if (Chi) split_store(a, Chi, Clo, idx);
        } else if (epi == 1) {
            a += (m == n) ? 1.f : 0.f;
            C[idx] = a;
            split_store(a, Chi, Clo, idx);
            float s = fabsf(a);                      // Gershgorin row-abs partial
            s += __shfl_xor(s, 1); s += __shfl_xor(s, 2);
            s += __shfl_xor(s, 4); s += __shfl_xor(s, 8);
            if (lr == 0) atomicAdd(&U[m], s);        // U carries rs here
        } else if (epi == 2) {
            a = 2.f * E[idx] - a;
            C[idx] = a;
            split_store(a, Chi, Clo, idx);
        } else if (epi == 6) {
            float z = a + E[idx] + v1[n];
            float xp = (1.0f - ALPHA) * z + ALPHA * Xtra[idx];
            split_store(xp, Chi, Clo, idx);
        } else if (epi == 8) {
            float z = a + E[idx] + v1[n];
            if (dtf[0] > 0.5f) ((__hip_bfloat16*)Out)[idx] = __float2bfloat16(z);
            else               ((float*)Out)[idx] = z;
        } else {  // 9: planes only
            split_store(a, Chi, Clo, idx);
        }
    }
}

// ---------------- single-plane bf16 NT GEMM (NS cheap iterations) ------------
// acc = A(bf16) x B(bf16), K=512, 16x64 tile. NS is self-correcting, so
// intermediate iterations need no hi/lo. mode 0: Ch = bf16(acc)  (U = X M)
// mode 1: v = 2*bf2f(Eh) - acc; Ch = bf16(v); if Cl: also lo plane + f32 Cf
__global__ __launch_bounds__(256) void sp_gemm_k(
    const short* __restrict__ Ab, const short* __restrict__ Bb,
    const short* __restrict__ Eh, short* __restrict__ Ch,
    short* __restrict__ Cl, float* __restrict__ Cf, int mode)
{
    __shared__ short As[16 * LDC];
    __shared__ short Bs[64 * LDC];
    const int tid = threadIdx.x;
    const int wv = tid >> 6, ln = tid & 63;
    const int quad = ln >> 4, lr = ln & 15;
    const int m0 = blockIdx.y * 16, n0 = blockIdx.x * 64;

    float4v acc1 = {0.f, 0.f, 0.f, 0.f};
    float4v acc2 = {0.f, 0.f, 0.f, 0.f};

    short8 pa, pb[4];
    {
        int row = tid >> 4, oct = tid & 15;
        pa = *(const short8*)(Ab + (size_t)(m0 + row) * 512 + oct * 8);
    }
    #pragma unroll
    for (int i = 0; i < 4; ++i) {
        int s = tid + 256 * i; int row = s >> 4, oct = s & 15;
        pb[i] = *(const short8*)(Bb + (size_t)(n0 + row) * 512 + oct * 8);
    }

    for (int c = 0; c < 4; ++c) {
        if (c) __syncthreads();
        {
            int row = tid >> 4, oct = tid & 15;
            *(short8*)&As[row * LDC + oct * 8] = pa;
        }
        #pragma unroll
        for (int i = 0; i < 4; ++i) {
            int s = tid + 256 * i; int row = s >> 4, oct = s & 15;
            *(short8*)&Bs[row * LDC + oct * 8] = pb[i];
        }
        __syncthreads();
        if (c + 1 < 4) {
            int kb = (c + 1) * CH;
            {
                int row = tid >> 4, oct = tid & 15;
                pa = *(const short8*)(Ab + (size_t)(m0 + row) * 512 + kb + oct * 8);
            }
            #pragma unroll
            for (int i = 0; i < 4; ++i) {
                int s = tid + 256 * i; int row = s >> 4, oct = s & 15;
                pb[i] = *(const short8*)(Bb + (size_t)(n0 + row) * 512 + kb + oct * 8);
            }
        }
        #pragma unroll
        for (int ks = 0; ks < 4; ++ks) {
            int ko = (ks * 4 + quad) * 8;
            short8 a = *(const short8*)&As[lr * LDC + ko];
            short8 b = *(const short8*)&Bs[(wv * 16 + lr) * LDC + ko];
            if (ks & 1) acc2 = __builtin_amdgcn_mfma_f32_16x16x32_bf16(a, b, acc2, 0, 0, 0);
            else        acc1 = __builtin_amdgcn_mfma_f32_16x16x32_bf16(a, b, acc1, 0, 0, 0);
        }
    }

    #pragma unroll
    for (int r = 0; r < 4; ++r) {
        int m = m0 + quad * 4 + r;
        int n = n0 + wv * 16 + lr;
        size_t idx = (size_t)m * 512 + n;
        float a = acc1[r] + acc2[r];
        if (mode == 0) {
            Ch[idx] = f2bf(a);
        } else {
            float v = 2.f * bf2f(Eh[idx]) - a;
            short hh = f2bf(v);
            Ch[idx] = hh;
            if (Cl) {
                Cl[idx] = f2bf(v - bf2f(hh));
                Cf[idx] = v;
            }
        }
    }
}

// ---------------- bf16-single-plane ADMM step GEMM ----------------
__global__ __launch_bounds__(256) void admm_bf16_k(
    const short* __restrict__ Ab, const short* __restrict__ Bb,
    const float* __restrict__ q0, const float* __restrict__ hF,
    float* __restrict__ uB, short* __restrict__ dh, short* __restrict__ dl)
{
    __shared__ short As[16 * LDC];
    __shared__ short Bs[64 * LDC];
    const int tid = threadIdx.x;
    const int wv = tid >> 6, ln = tid & 63;
    const int quad = ln >> 4, lr = ln & 15;
    const int m0 = blockIdx.y * 16, n0 = blockIdx.x * 64;

    float4v acc1 = {0.f, 0.f, 0.f, 0.f};
    float4v acc2 = {0.f, 0.f, 0.f, 0.f};

    short8 pa, pb[4];
    {
        int row = tid >> 4, oct = tid & 15;
        pa = *(const short8*)(Ab + (size_t)(m0 + row) * 512 + oct * 8);
    }
    #pragma unroll
    for (int i = 0; i < 4; ++i) {
        int s = tid + 256 * i; int row = s >> 4, oct = s & 15;
        pb[i] = *(const short8*)(Bb + (size_t)(n0 + row) * 512 + oct * 8);
    }

    for (int c = 0; c < 4; ++c) {
        if (c) __syncthreads();
        {
            int row = tid >> 4, oct = tid & 15;
            *(short8*)&As[row * LDC + oct * 8] = pa;
        }
        #pragma unroll
        for (int i = 0; i < 4; ++i) {
            int s = tid + 256 * i; int row = s >> 4, oct = s & 15;
            *(short8*)&Bs[row * LDC + oct * 8] = pb[i];
        }
        __syncthreads();
        if (c + 1 < 4) {
            int kb = (c + 1) * CH;
            {
                int row = tid >> 4, oct = tid & 15;
                pa = *(const short8*)(Ab + (size_t)(m0 + row) * 512 + kb + oct * 8);
            }
            #pragma unroll
            for (int i = 0; i < 4; ++i) {
                int s = tid + 256 * i; int row = s >> 4, oct = s & 15;
                pb[i] = *(const short8*)(Bb + (size_t)(n0 + row) * 512 + kb + oct * 8);
            }
        }
        #pragma unroll
        for (int ks = 0; ks < 4; ++ks) {
            int ko = (ks * 4 + quad) * 8;
            short8 a = *(const short8*)&As[lr * LDC + ko];
            short8 b = *(const short8*)&Bs[(wv * 16 + lr) * LDC + ko];
            if (ks & 1) acc2 = __builtin_amdgcn_mfma_f32_16x16x32_bf16(a, b, acc2, 0, 0, 0);
            else        acc1 = __builtin_amdgcn_mfma_f32_16x16x32_bf16(a, b, acc1, 0, 0, 0);
        }
    }

    #pragma unroll
    for (int r = 0; r < 4; ++r) {
        int m = m0 + quad * 4 + r;
        int n = n0 + wv * 16 + lr;
        size_t idx = (size_t)m * 512 + n;
        float gz = acc1[r] + acc2[r] + q0[idx];
        float hn = hF[n];
        float w = hn - gz - uB[idx];
        uB[idx] = fmaxf(0.f, -w);
        float t2 = hn - fabsf(w);
        short hh = f2bf(t2);
        dh[idx] = hh;
        if (dl) dl[idx] = f2bf(t2 - bf2f(hh));
    }
}

// ---------------- host launcher ----------------

extern "C" void kernel_launch(void* const* d_in, const int* in_sizes, int n_in,
                              void* d_out, int out_size, void* d_ws, size_t ws_size,
                              hipStream_t stream) {
    const void* c_raw = d_in[0];
    const void* G_raw = d_in[1];
    const void* h_raw = d_in[2];
    const void* A_raw = d_in[3];
    const void* b_raw = d_in[4];

    float* w = (float*)d_ws;
    size_t o = 0;
    auto alloc = [&](size_t n) { float* p = w + o; o += (n + 63) & ~(size_t)63; return p; };

    float* cF  = alloc(BB * NN);
    float* GF  = alloc(MI * NN);
    float* AF  = alloc(ME * NN);
    float* hF  = alloc(MI);
    float* bF  = alloc(ME);
    float* Mm  = alloc(NN * NN);
    float* Xf0 = alloc(NN * NN);
    float* Xf1 = alloc(NN * NN);
    float* Rf  = alloc(MI * NN);
    float* Y   = alloc(NN * ME);
    float* T1  = alloc(NN * ME);
    float* Si  = alloc(ME * ME);
    float* zb  = alloc(NN);
    float* g0  = alloc(MI);
    float* rs  = alloc(NN);
    float* dtf = alloc(16);
    float* q0  = alloc(BB * MI);
    float* xW  = alloc(BB * NN);
    float* uB  = alloc(BB * MI);

    short* sbp = (short*)(w + o);
    size_t so = 0;
    auto allocS = [&](size_t n) { short* p = sbp + so; so += (n + 127) & ~(size_t)127; return p; };

    // Bcat = [G(512) ; R(512) ; W1(512)] x 512, contiguous per plane
    short* Bcat_h = allocS(3 * 512 * 512);
    short* Bcat_l = allocS(3 * 512 * 512);
    short* GFh = Bcat_h;              short* GFl = Bcat_l;
    short* Rh  = Bcat_h + 512 * 512;  short* Rl  = Bcat_l + 512 * 512;
    short* W1h = Bcat_h + 1024 * 512; short* W1l = Bcat_l + 1024 * 512;

    short* GTh = allocS(NN * MI);  short* GTl = allocS(NN * MI);
    short* Mmh = allocS(NN * NN);  short* Mml = allocS(NN * NN);
    short* X0h = allocS(NN * NN);  short* X0l = allocS(NN * NN);
    short* X1h = allocS(NN * NN);  short* X1l = allocS(NN * NN);
    short* Uh  = allocS(NN * NN);  short* Ul  = allocS(NN * NN);
    short* RTh = allocS(NN * MI);  short* RTl = allocS(NN * MI);
    short* Qh  = allocS(MI * MI);  short* Ql  = allocS(MI * MI);
    short* xh  = allocS(BB * NN);  short* xl  = allocS(BB * NN);
    short* tAh = allocS(BB * MI);  short* tAl = allocS(BB * MI);
    short* tBh = allocS(BB * MI);  short* tBl = allocS(BB * MI);

    dim3 blk(256);
    auto cdiv = [](int a, int b) { return (a + b - 1) / b; };
    dim3 gSq(8, 32);    // 512x512 outputs
    dim3 gBt(8, 64);    // 1024x512 outputs
    dim3 gCombo(24, 64);

    detect_dtype_k<<<1, 256, 0, stream>>>((const unsigned short*)G_raw, dtf);
    ingest_all_k<<<cdiv(BB * NN, 256), blk, 0, stream>>>(
        c_raw, G_raw, h_raw, A_raw, b_raw,
        cF, xh, xl, GF, GFh, GFl, hF, AF, bF, rs, dtf);

    // G^T planes
    transpose_split_k<<<dim3(16, 16), blk, 0, stream>>>(GF, GTh, GTl);

    // M = I + G^T G  (f32 + planes + Gershgorin row-abs atomics into rs)
    mfma_gemm2<<<gSq, blk, 0, stream>>>(GTh, GTl, GTh, GTl, Mm, Mmh, Mml,
                                        nullptr, nullptr, rs, nullptr, nullptr, nullptr, 1);

    // X1 = 2c0 I - c0^2 M  (bf16-hi only; skips the first NS pair)
    initX1_k<<<256, blk, 0, stream>>>(rs, Mm, X0h);

    // NS cheap iterations (single-plane): X2..X6; last pair emits hi/lo + f32
    short* XcurH = X0h;
    short* XnxtH = X1h;
    for (int it = 0; it < NS_CHEAP; ++it) {
        bool last = (it == NS_CHEAP - 1);
        sp_gemm_k<<<gSq, blk, 0, stream>>>(XcurH, Mmh, nullptr, Uh, nullptr, nullptr, 0);
        short* nl = last ? ((XnxtH == X0h) ? X0l : X1l) : nullptr;
        float* nf = last ? ((XnxtH == X0h) ? Xf0 : Xf1) : nullptr;
        sp_gemm_k<<<gSq, blk, 0, stream>>>(Uh, XcurH, XcurH, XnxtH, nl, nf, 1);
        short* t = XcurH; XcurH = XnxtH; XnxtH = t;
    }
    // NS_CHEAP=5 odd -> X6 in X1h/X1l/Xf1
    // Final hi/lo pair: U = X6 M; X7 = 2 X6 - U X6  -> Xf0/X0h/X0l
    mfma_gemm2<<<gSq, blk, 0, stream>>>(X1h, X1l, Mmh, Mml, nullptr, Uh, Ul,
                                        nullptr, nullptr, nullptr, nullptr, nullptr, nullptr, 9);
    mfma_gemm2<<<gSq, blk, 0, stream>>>(Uh, Ul, X1h, X1l, Xf0, X0h, X0l,
                                        Xf1, nullptr, nullptr, nullptr, nullptr, nullptr, 2);
    float* Minv = Xf0;

    // Schur pieces
    Y_k<<<NN, blk, 0, stream>>>(Minv, AF, Y);
    sm_inv_k<<<1, blk, 0, stream>>>(AF, Y, Si);
    T1zb_k<<<NN / 16, blk, 0, stream>>>(Y, Si, bF, T1, zb);
    W1_k<<<NN * NN / 256, blk, 0, stream>>>(Minv, T1, Y, W1h, W1l);

    // R = G W1 (f32 + planes into Bcat R slice)
    mfma_gemm2<<<gSq, blk, 0, stream>>>(GFh, GFl, W1h, W1l, Rf, Rh, Rl,
                                        nullptr, nullptr, nullptr, nullptr, nullptr, nullptr, 0);
    transpose_split_k<<<dim3(16, 16), blk, 0, stream>>>(Rf, RTh, RTl);
    // Q = R G^T (planes; ADMM uses hi only)
    mfma_gemm2<<<gSq, blk, 0, stream>>>(Rh, Rl, GFh, GFl, nullptr, Qh, Ql,
                                        nullptr, nullptr, nullptr, nullptr, nullptr, nullptr, 9);
    g0_k<<<NN / 4, blk, 0, stream>>>(GF, zb, g0);

    // 4 projections (x0 = c, planes already in xh/xl from ingest)
    for (int p = 0; p < 4; ++p) {
        // combo: [t0-init | q0 | xW] in one launch, B = [G;R;W1]
        mfma_gemm2<<<gCombo, blk, 0, stream>>>(xh, xl, Bcat_h, Bcat_l, q0, tAh, tAl,
                                               g0, hF, uB, xW, nullptr, nullptr, 7);
        for (int it = 0; it < ADMM_IT; ++it) {
            const short* sh = (it & 1) ? tBh : tAh;
            short* dh = (it & 1) ? tAh : tBh;
            short* dl = (it == ADMM_IT - 1) ? tBl : nullptr;  // last iter -> lo plane too
            admm_bf16_k<<<gBt, blk, 0, stream>>>(sh, Qh, q0, hF, uB, dh, dl);
        }
        // final z = t R + xW + zb (t in tB hi/lo after 15 iters); PGD split or emit
        if (p < 3) {
            mfma_gemm2<<<gBt, blk, 0, stream>>>(tBh, tBl, RTh, RTl, nullptr, xh, xl,
                                                xW, zb, nullptr, cF, nullptr, nullptr, 6);
        } else {
            mfma_gemm2<<<gBt, blk, 0, stream>>>(tBh, tBl, RTh, RTl, nullptr, nullptr, nullptr,
                                                xW, zb, nullptr, nullptr, dtf, d_out, 8);
        }
    }
}